// Round 18
// baseline (624.849 us; speedup 1.0000x reference)
//
#include <hip/hip_runtime.h>
#include <math.h>

#define R_TOT 4096   // B*S
#define E_DIM 1024
#define M_DIM 16384
#define H_NUM 16
#define HD    64
#define SEQ   2048
#define BATCH 2
#define TOPK  8
#define MIDK  16
#define NCHUNK 16
#define SCHUNK 1024
#define CANDS  32

typedef __attribute__((ext_vector_type(8))) short short8_t;
typedef __attribute__((ext_vector_type(4))) float f32x4;

__device__ inline unsigned short f2bf(float x) {
  unsigned u = __float_as_uint(x);
  u = (u + 0x7fff + ((u >> 16) & 1)) >> 16;
  return (unsigned short)u;
}
__device__ inline float bf2f(unsigned short h) {
  return __uint_as_float(((unsigned)h) << 16);
}

#define GLDS16(gp, lp) __builtin_amdgcn_global_load_lds( \
    (const __attribute__((address_space(1))) void*)(gp), \
    (__attribute__((address_space(3))) void*)(lp), 16, 0, 0)

// ---------------- fused L2-normalize + bf16 cast (+ raw bf16 + rinv) ----------------
__global__ __launch_bounds__(256) void norm_bf16_kernel(const float* __restrict__ X,
                                                        unsigned short* __restrict__ Y,
                                                        unsigned short* __restrict__ Yraw,
                                                        float* __restrict__ rinv_out) {
  int row = blockIdx.x;
  int tid = threadIdx.x;
  const float4* xr = (const float4*)(X + (size_t)row * E_DIM);
  float4 v = xr[tid];
  float s = v.x*v.x + v.y*v.y + v.z*v.z + v.w*v.w;
  #pragma unroll
  for (int off = 32; off; off >>= 1) s += __shfl_down(s, off, 64);
  __shared__ float wsum[4];
  if ((tid & 63) == 0) wsum[tid >> 6] = s;
  __syncthreads();
  float tot = wsum[0] + wsum[1] + wsum[2] + wsum[3];
  float rinv = 1.0f / fmaxf(sqrtf(tot), 1e-12f);
  if (tid == 0) rinv_out[row] = rinv;
  ushort4 o;
  o.x = f2bf(v.x * rinv); o.y = f2bf(v.y * rinv);
  o.z = f2bf(v.z * rinv); o.w = f2bf(v.w * rinv);
  ((ushort4*)(Y + (size_t)row * E_DIM))[tid] = o;
  if (Yraw) {
    ushort4 o2;
    o2.x = f2bf(v.x); o2.y = f2bf(v.y); o2.z = f2bf(v.z); o2.w = f2bf(v.w);
    ((ushort4*)(Yraw + (size_t)row * E_DIM))[tid] = o2;
  }
}

// ---------------- fp32 -> bf16 cast ----------------
__global__ __launch_bounds__(256) void cast_bf16_kernel(const float* __restrict__ X,
                                                        unsigned short* __restrict__ Y, int n4) {
  int i = blockIdx.x * 256 + threadIdx.x;
  if (i < n4) {
    float4 v = ((const float4*)X)[i];
    ushort4 o;
    o.x = f2bf(v.x); o.y = f2bf(v.y); o.z = f2bf(v.z); o.w = f2bf(v.w);
    ((ushort4*)Y)[i] = o;
  }
}

// ---------------- pipelined MFMA 128x128 tile body (QUAD-buffer, single barrier/step) ----------------
template<int OUT_BF16>
__device__ __forceinline__ void gemm_tile_body_pipe(
    const unsigned short* __restrict__ Ab, const unsigned short* __restrict__ Bb,
    const float* __restrict__ bias, void* __restrict__ C, int N,
    int bm, int bn, char* pool) {
  int tid = threadIdx.x;
  int wave = tid >> 6, lane = tid & 63;
  int wr = wave >> 1, wc = wave & 1;
  int li8 = lane >> 3;
  int gslot = (lane & 7) ^ li8;

  auto STAGE = [&](int d, int k0) {   // 8 GLDS16 per thread -> 32KB tile
    #pragma unroll
    for (int s4 = 0; s4 < 8; ++s4) {
      int s = wave * 8 + s4;
      const unsigned short* gp;
      if (s < 16) {
        int r = s * 8 + li8;
        gp = Ab + (size_t)(bm + r) * E_DIM + k0 + gslot * 8;
      } else {
        int r = (s - 16) * 8 + li8;
        gp = Bb + (size_t)(bn + r) * E_DIM + k0 + gslot * 8;
      }
      GLDS16(gp, pool + d * 32768 + s * 1024);
    }
  };

  f32x4 acc[4][4];
  #pragma unroll
  for (int i = 0; i < 4; ++i)
    #pragma unroll
    for (int j = 0; j < 4; ++j)
      acc[i][j] = (f32x4){0.f, 0.f, 0.f, 0.f};

  STAGE(0, 0);
  STAGE(1, 64);

  const int NT = E_DIM / 64;   // 16 steps
  for (int t = 0; t < NT; ++t) {
    int cur = t & 3;
    if (t + 2 < NT) {
      STAGE((t + 2) & 3, (t + 2) * 64);
      asm volatile("s_waitcnt vmcnt(16)" ::: "memory");  // tile-t's 8 landed; t+1,t+2 (16) in flight
    } else if (t + 1 < NT) {
      asm volatile("s_waitcnt vmcnt(8)" ::: "memory");
    } else {
      asm volatile("s_waitcnt vmcnt(0)" ::: "memory");
    }
    __builtin_amdgcn_s_barrier();          // single barrier/step (quad-buffer skew argument)
    __builtin_amdgcn_sched_barrier(0);
    short* Ap = (short*)(pool + cur * 32768);
    short* Bp = (short*)(pool + cur * 32768 + 16384);
    #pragma unroll
    for (int ks = 0; ks < 2; ++ks) {
      short8_t af[4], bf[4];
      int kslot = ks * 4 + (lane >> 4);
      #pragma unroll
      for (int mi = 0; mi < 4; ++mi) {
        int r = wr * 64 + mi * 16 + (lane & 15);
        af[mi] = *(const short8_t*)(Ap + r * 64 + ((kslot ^ (r & 7)) * 8));
      }
      #pragma unroll
      for (int ni = 0; ni < 4; ++ni) {
        int r = wc * 64 + ni * 16 + (lane & 15);
        bf[ni] = *(const short8_t*)(Bp + r * 64 + ((kslot ^ (r & 7)) * 8));
      }
      #pragma unroll
      for (int mi = 0; mi < 4; ++mi)
        #pragma unroll
        for (int ni = 0; ni < 4; ++ni)
          acc[mi][ni] = __builtin_amdgcn_mfma_f32_16x16x32_bf16(af[mi], bf[ni], acc[mi][ni], 0, 0, 0);
    }
    __builtin_amdgcn_sched_barrier(0);
  }
  #pragma unroll
  for (int mi = 0; mi < 4; ++mi) {
    #pragma unroll
    for (int ni = 0; ni < 4; ++ni) {
      int col = bn + wc * 64 + ni * 16 + (lane & 15);
      float bv = bias[col];
      #pragma unroll
      for (int r = 0; r < 4; ++r) {
        int row = bm + wr * 64 + mi * 16 + (lane >> 4) * 4 + r;
        float v = acc[mi][ni][r] + bv;
        if (OUT_BF16)
          ((unsigned short*)C)[(size_t)row * N + col] = f2bf(v);
        else
          ((float*)C)[(size_t)row * N + col] = v;
      }
    }
  }
}

// ---------------- output GEMM: C = A * Wo^T + bo (fp32 out) ----------------
__global__ __launch_bounds__(256) void mfma_gemm_out(
    const unsigned short* __restrict__ Ab, const unsigned short* __restrict__ Bb,
    const float* __restrict__ bias, float* __restrict__ C) {
  __shared__ __align__(16) char pool[131072];
  gemm_tile_body_pipe<0>(Ab, Bb, bias, C, E_DIM, blockIdx.x * 128, blockIdx.y * 128, pool);
}

// ---------------- batched QKV GEMM: grid.y covers N=3072 ----------------
__global__ __launch_bounds__(256) void mfma_gemm_qkv(
    const unsigned short* __restrict__ hb,
    const unsigned short* __restrict__ wq, const unsigned short* __restrict__ wk,
    const unsigned short* __restrict__ wv,
    const float* __restrict__ bq, const float* __restrict__ bk, const float* __restrict__ bv,
    unsigned short* __restrict__ q_b, unsigned short* __restrict__ k_b,
    unsigned short* __restrict__ v_b) {
  __shared__ __align__(16) char pool[131072];
  int bn_g = blockIdx.y * 128;
  int sel = bn_g >> 10;
  int bn = bn_g & 1023;
  const unsigned short* Bb = (sel == 0) ? wq : (sel == 1) ? wk : wv;
  const float* bias = (sel == 0) ? bq : (sel == 1) ? bk : bv;
  unsigned short* C = (sel == 0) ? q_b : (sel == 1) ? k_b : v_b;
  gemm_tile_body_pipe<1>(hb, Bb, bias, C, E_DIM, blockIdx.x * 128, bn, pool);
}

// ---------------- V transpose: vb[b][s][h][d] -> vT[b][h][d][s] (bf16) ----------------
__global__ __launch_bounds__(256) void vtrans_kernel(const unsigned short* __restrict__ vb,
                                                     unsigned short* __restrict__ vT) {
  int st = blockIdx.x;
  int bh = blockIdx.y;
  int b = bh >> 4, h = bh & 15;
  __shared__ short T[64][72];
  int tid = threadIdx.x;
  #pragma unroll
  for (int it = 0; it < 2; ++it) {
    int idx = tid + it * 256;
    int r = idx >> 3, sl = idx & 7;
    short8_t v = *(const short8_t*)(vb + ((size_t)(b * SEQ + st * 64 + r)) * E_DIM + h * HD + sl * 8);
    *(short8_t*)&T[r][sl * 8] = v;
  }
  __syncthreads();
  int d = tid >> 2, sp = (tid & 3) * 16;
  short8_t o0, o1;
  #pragma unroll
  for (int u = 0; u < 8; ++u) o0[u] = T[sp + u][d];
  #pragma unroll
  for (int u = 0; u < 8; ++u) o1[u] = T[sp + 8 + u][d];
  size_t base = ((size_t)bh * HD + d) * SEQ + st * 64 + sp;
  *(short8_t*)(vT + base) = o0;
  *(short8_t*)(vT + base + 8) = o1;
}

// ---------------- MFMA bf16 sims GEMM + fused top-8: 8-wave QUAD-buffer, ONE barrier/step ----------------
#define NSTEP (SCHUNK / 128 * 16)   // 128 K-steps (8 subtiles x 16)

__global__ __launch_bounds__(512) void sims_topk_kernel(
    const unsigned short* __restrict__ Hn, const unsigned short* __restrict__ MKn,
    float* __restrict__ cand_v, int* __restrict__ cand_i) {
  __shared__ __align__(16) char pool[131072];   // buf0..buf3, 32KB each

  int bm = blockIdx.x * 128;
  int chunk = blockIdx.y;

  int tid = threadIdx.x;
  int wave = tid >> 6, lane = tid & 63;
  int wr = wave >> 2, wc = wave & 3;          // 2x4 wave grid, wave tile 64x32
  int srow = tid >> 2, sl = tid & 3;          // scan: 4 lanes/row, 32 cols each
  int li8 = lane >> 3;
  int gslot = (lane & 7) ^ li8;

  float tv[TOPK]; int ti[TOPK];
  #pragma unroll
  for (int u = 0; u < TOPK; ++u) { tv[u] = -INFINITY; ti[u] = 0; }

  auto STAGE = [&](int d, int t) {    // 4 GLDS16 per thread -> 32KB tile
    int sub = t >> 4;
    int k0 = (t & 15) * 64;
    int bn = chunk * SCHUNK + sub * 128;
    #pragma unroll
    for (int s4 = 0; s4 < 4; ++s4) {
      int s = wave * 4 + s4;
      const unsigned short* gp;
      if (s < 16) {
        int r = s * 8 + li8;
        gp = Hn + (size_t)(bm + r) * E_DIM + k0 + gslot * 8;
      } else {
        int r = (s - 16) * 8 + li8;
        gp = MKn + (size_t)(bn + r) * E_DIM + k0 + gslot * 8;
      }
      GLDS16(gp, pool + d * 32768 + s * 1024);
    }
  };

  f32x4 acc[4][2];
  #pragma unroll
  for (int i = 0; i < 4; ++i)
    #pragma unroll
    for (int j = 0; j < 2; ++j)
      acc[i][j] = (f32x4){0.f, 0.f, 0.f, 0.f};

  STAGE(0, 0);
  STAGE(1, 1);

  for (int t = 0; t < NSTEP; ++t) {
    int cur = t & 3;
    if (t + 2 < NSTEP) {
      STAGE((t + 2) & 3, t + 2);
      asm volatile("s_waitcnt vmcnt(8)" ::: "memory");   // tile-t's 4 landed (t+1,t+2 in flight)
    } else if (t + 1 < NSTEP) {
      asm volatile("s_waitcnt vmcnt(4)" ::: "memory");
    } else {
      asm volatile("s_waitcnt vmcnt(0)" ::: "memory");
    }
    __builtin_amdgcn_s_barrier();          // single barrier per step
    __builtin_amdgcn_sched_barrier(0);

    short* Ap = (short*)(pool + cur * 32768);
    short* Bp = (short*)(pool + cur * 32768 + 16384);
    #pragma unroll
    for (int ks = 0; ks < 2; ++ks) {
      short8_t af[4], bf[2];
      int kslot = ks * 4 + (lane >> 4);
      #pragma unroll
      for (int mi = 0; mi < 4; ++mi) {
        int r = wr * 64 + mi * 16 + (lane & 15);
        af[mi] = *(const short8_t*)(Ap + r * 64 + ((kslot ^ (r & 7)) * 8));
      }
      #pragma unroll
      for (int ni = 0; ni < 2; ++ni) {
        int r = wc * 32 + ni * 16 + (lane & 15);
        bf[ni] = *(const short8_t*)(Bp + r * 64 + ((kslot ^ (r & 7)) * 8));
      }
      #pragma unroll
      for (int mi = 0; mi < 4; ++mi)
        #pragma unroll
        for (int ni = 0; ni < 2; ++ni)
          acc[mi][ni] = __builtin_amdgcn_mfma_f32_16x16x32_bf16(af[mi], bf[ni], acc[mi][ni], 0, 0, 0);
    }
    __builtin_amdgcn_sched_barrier(0);

    if ((t & 15) == 15) {
      __builtin_amdgcn_s_barrier();   // all waves done reading buf[cur] before scan overwrites
      short* Sp = (short*)(pool + cur * 32768);
      int bn = chunk * SCHUNK + (t >> 4) * 128;
      #pragma unroll
      for (int mi = 0; mi < 4; ++mi) {
        #pragma unroll
        for (int ni = 0; ni < 2; ++ni) {
          int scol = wc * 32 + ni * 16 + (lane & 15);
          #pragma unroll
          for (int r = 0; r < 4; ++r) {
            int srw = wr * 64 + mi * 16 + (lane >> 4) * 4 + r;
            Sp[srw * 128 + (scol ^ ((srw & 15) << 3))] = (short)f2bf(acc[mi][ni][r]);
          }
          acc[mi][ni] = (f32x4){0.f, 0.f, 0.f, 0.f};
        }
      }
      __syncthreads();
      #pragma unroll
      for (int u4 = 0; u4 < 8; ++u4) {
        int col = sl * 32 + u4 * 4;
        const short* p = Sp + srow * 128 + (col ^ ((srow & 15) << 3));
        short4 v4 = *(const short4*)p;
        short vv[4] = {v4.x, v4.y, v4.z, v4.w};
        #pragma unroll
        for (int j = 0; j < 4; ++j) {
          float v = bf2f((unsigned short)vv[j]);
          if (v > tv[0]) {
            int idx = bn + col + j;
            int p_ = 0;
            #pragma unroll
            for (int q = 1; q < TOPK; ++q)
              if (v > tv[q]) { tv[q-1] = tv[q]; ti[q-1] = ti[q]; p_ = q; }
            tv[p_] = v; ti[p_] = idx;
          }
        }
      }
      __syncthreads();   // scan done before buf[cur] restaged (at step t+2)
    }
  }
  size_t base = (((size_t)(bm + srow)) * NCHUNK + chunk) * CANDS + sl * TOPK;
  #pragma unroll
  for (int u = 0; u < TOPK; ++u) { cand_v[base + u] = tv[u]; cand_i[base + u] = ti[u]; }
}

// ---------------- merge 512 candidates/row -> top-16 (bf16-order) ----------------
__global__ __launch_bounds__(64) void merge_topk_kernel(
    const float* __restrict__ cand_v, const int* __restrict__ cand_i,
    int* __restrict__ mid_i) {
  int row = blockIdx.x;
  int lane = threadIdx.x;
  size_t base = (size_t)row * (NCHUNK * CANDS);
  float v[8]; int id[8];
  #pragma unroll
  for (int u = 0; u < 8; ++u) {
    v[u]  = cand_v[base + lane*8 + u];
    id[u] = cand_i[base + lane*8 + u];
  }
  for (int t = 0; t < MIDK; ++t) {
    float bvv = v[0]; int bu = 0;
    #pragma unroll
    for (int u = 1; u < 8; ++u) if (v[u] > bvv) { bvv = v[u]; bu = u; }
    float mv = bvv; int ml = lane;
    #pragma unroll
    for (int off = 32; off; off >>= 1) {
      float ov = __shfl_down(mv, off, 64);
      int   ol = __shfl_down(ml, off, 64);
      if (ov > mv) { mv = ov; ml = ol; }
    }
    ml = __shfl(ml, 0, 64);
    if (lane == ml) {
      mid_i[(size_t)row * MIDK + t] = id[bu];
      v[bu] = -INFINITY;
    }
  }
}

// ---------------- exact fp32 refine: 16 candidates -> true top-8 ----------------
__global__ __launch_bounds__(256) void refine_kernel(
    const float* __restrict__ hidden, const float* __restrict__ mkeys,
    const float* __restrict__ rinvH, const float* __restrict__ rinvK,
    const int* __restrict__ mid_i,
    float* __restrict__ top_v, int* __restrict__ top_i) {
  int row = blockIdx.x;
  int tid = threadIdx.x;
  int wave = tid >> 6, lane = tid & 63;
  __shared__ float hrow[E_DIM];
  __shared__ float rv[MIDK];
  __shared__ int   ri[MIDK];
  ((float4*)hrow)[tid] = ((const float4*)(hidden + (size_t)row * E_DIM))[tid];
  __syncthreads();
  float rh = rinvH[row];
  for (int c = wave; c < MIDK; c += 4) {
    int idx = mid_i[(size_t)row * MIDK + c];
    const float* kp = mkeys + (size_t)idx * E_DIM;
    float s = 0.f;
    #pragma unroll
    for (int rr = 0; rr < 4; ++rr) {
      float4 kv = *(const float4*)(kp + rr * 256 + lane * 4);
      float4 hv = *(const float4*)(hrow + rr * 256 + lane * 4);
      s += hv.x*kv.x + hv.y*kv.y + hv.z*kv.z + hv.w*kv.w;
    }
    #pragma unroll
    for (int off = 32; off; off >>= 1) s += __shfl_down(s, off, 64);
    if (lane == 0) { rv[c] = s * rh * rinvK[idx]; ri[c] = idx; }
  }
  __syncthreads();
  if (tid == 0) {
    bool used[MIDK] = {};
    #pragma unroll
    for (int t = 0; t < TOPK; ++t) {
      float best = -INFINITY; int bi = -1; int bidx = 0x7fffffff;
      for (int c = 0; c < MIDK; ++c) {
        if (used[c]) continue;
        if (rv[c] > best || (rv[c] == best && ri[c] < bidx)) {
          best = rv[c]; bi = c; bidx = ri[c];
        }
      }
      used[bi] = true;
      top_v[(size_t)row * TOPK + t] = best;
      top_i[(size_t)row * TOPK + t] = bidx;
    }
  }
}

// ---------------- MFMA flash attention: Q-in-LDS + QUAD K/V + single barrier/step ----------------
__global__ __launch_bounds__(256) void flash_mfma_kernel(
    const unsigned short* __restrict__ qb, const unsigned short* __restrict__ kb,
    const unsigned short* __restrict__ vT, const float* __restrict__ MV,
    const float* __restrict__ top_v, const int* __restrict__ top_i,
    unsigned short* __restrict__ ctx) {
  __shared__ __align__(16) char pool[98304];   // Qs 16K | KV buf0..3 16K each | P 16K
  short* Qs = (short*)pool;
  int qt = blockIdx.x;
  int bh = blockIdx.y;
  int b = bh >> 4, h = bh & 15;
  int tid = threadIdx.x;
  int wave = tid >> 6, lane = tid & 63;
  int g = lane >> 4, c = lane & 15;
  int li8 = lane >> 3;
  int gslot = (lane & 7) ^ li8;
  short* Pw = (short*)(pool + 81920 + wave * 4096);
  const float scale = 0.125f;

  auto STAGEKV = [&](int d, int kv0) {   // 4 GLDS16/thread -> 16KB (K 8K | V 8K)
    #pragma unroll
    for (int j = 0; j < 4; ++j) {
      int s = wave * 4 + j;
      const unsigned short* gp;
      if (s < 8) {
        int r = s * 8 + li8;
        gp = kb + ((size_t)(b * SEQ + kv0 + r)) * E_DIM + h * HD + gslot * 8;
      } else {
        int dd = (s - 8) * 8 + li8;
        gp = vT + ((size_t)(bh * HD + dd)) * SEQ + kv0 + gslot * 8;
      }
      GLDS16(gp, pool + 16384 + d * 16384 + s * 1024);
    }
  };

  #pragma unroll
  for (int j = 0; j < 4; ++j) {
    int s = wave * 4 + j;
    int r = s * 8 + li8;
    const unsigned short* gp = qb + ((size_t)(b * SEQ) + qt * 128 + r) * E_DIM + h * HD + gslot * 8;
    GLDS16(gp, pool + s * 1024);
  }
  STAGEKV(0, 0);
  STAGEKV(1, 64);
  __syncthreads();   // full drain: Q + tiles 0,1 ready

  short8_t aQ[2][2];
  #pragma unroll
  for (int mi = 0; mi < 2; ++mi)
    #pragma unroll
    for (int ks = 0; ks < 2; ++ks) {
      int r = wave * 32 + mi * 16 + c;
      int slot = ks * 4 + g;
      aQ[mi][ks] = *(const short8_t*)(Qs + r * 64 + ((slot ^ (r & 7)) * 8));
    }

  f32x4 oa[2][4];
  #pragma unroll
  for (int mi = 0; mi < 2; ++mi)
    #pragma unroll
    for (int nd = 0; nd < 4; ++nd)
      oa[mi][nd] = (f32x4){0.f, 0.f, 0.f, 0.f};
  float m_[2][4], l_[2][4];
  #pragma unroll
  for (int mi = 0; mi < 2; ++mi)
    #pragma unroll
    for (int r = 0; r < 4; ++r) { m_[mi][r] = -INFINITY; l_[mi][r] = 0.f; }

  const int NKT = SEQ / 64;   // 32 steps
  for (int kt = 0; kt < NKT; ++kt) {
    int cur = kt & 3;
    if (kt + 2 < NKT) {
      STAGEKV((kt + 2) & 3, (kt + 2) * 64);
      asm volatile("s_waitcnt vmcnt(8)" ::: "memory");   // tile-kt's 4 landed
    } else if (kt + 1 < NKT) {
      asm volatile("s_waitcnt vmcnt(4)" ::: "memory");
    } else {
      asm volatile("s_waitcnt vmcnt(0)" ::: "memory");
    }
    __builtin_amdgcn_s_barrier();          // single barrier/step (quad skew argument)
    __builtin_amdgcn_sched_barrier(0);
    short* Kp = (short*)(pool + 16384 + cur * 16384);
    short* Vp = (short*)(pool + 16384 + cur * 16384 + 8192);

    f32x4 sa[2][4];
    #pragma unroll
    for (int mi = 0; mi < 2; ++mi)
      #pragma unroll
      for (int ni = 0; ni < 4; ++ni)
        sa[mi][ni] = (f32x4){0.f, 0.f, 0.f, 0.f};
    #pragma unroll
    for (int ks = 0; ks < 2; ++ks) {
      short8_t bK[4];
      #pragma unroll
      for (int ni = 0; ni < 4; ++ni) {
        int r = ni * 16 + c;
        bK[ni] = *(const short8_t*)(Kp + r * 64 + (((ks * 4 + g) ^ (r & 7)) * 8));
      }
      #pragma unroll
      for (int mi = 0; mi < 2; ++mi)
        #pragma unroll
        for (int ni = 0; ni < 4; ++ni)
          sa[mi][ni] = __builtin_amdgcn_mfma_f32_16x16x32_bf16(aQ[mi][ks], bK[ni], sa[mi][ni], 0, 0, 0);
    }
    #pragma unroll
    for (int mi = 0; mi < 2; ++mi)
      #pragma unroll
      for (int ni = 0; ni < 4; ++ni)
        #pragma unroll
        for (int r = 0; r < 4; ++r)
          sa[mi][ni][r] *= scale;
    float fsc[2][4];
    #pragma unroll
    for (int mi = 0; mi < 2; ++mi)
      #pragma unroll
      for (int r = 0; r < 4; ++r) {
        float m0 = fmaxf(fmaxf(sa[mi][0][r], sa[mi][1][r]), fmaxf(sa[mi][2][r], sa[mi][3][r]));
        #pragma unroll
        for (int off = 1; off < 16; off <<= 1) m0 = fmaxf(m0, __shfl_xor(m0, off, 64));
        float mn = fmaxf(m_[mi][r], m0);
        fsc[mi][r] = __expf(m_[mi][r] - mn);
        m_[mi][r] = mn;
      }
    #pragma unroll
    for (int mi = 0; mi < 2; ++mi)
      #pragma unroll
      for (int nd = 0; nd < 4; ++nd)
        #pragma unroll
        for (int r = 0; r < 4; ++r)
          oa[mi][nd][r] *= fsc[mi][r];
    #pragma unroll
    for (int mi = 0; mi < 2; ++mi)
      #pragma unroll
      for (int r = 0; r < 4; ++r) {
        float ps = 0.f;
        #pragma unroll
        for (int ni = 0; ni < 4; ++ni) {
          float p = __expf(sa[mi][ni][r] - m_[mi][r]);
          sa[mi][ni][r] = p;
          ps += p;
        }
        #pragma unroll
        for (int off = 1; off < 16; off <<= 1) ps += __shfl_xor(ps, off, 64);
        l_[mi][r] = l_[mi][r] * fsc[mi][r] + ps;
      }
    // P is wave-private LDS: same-wave write->read needs only lgkmcnt (compiler-inserted)
    #pragma unroll
    for (int mi = 0; mi < 2; ++mi)
      #pragma unroll
      for (int ni = 0; ni < 4; ++ni)
        #pragma unroll
        for (int r = 0; r < 4; ++r) {
          int ql = mi * 16 + g * 4 + r;
          int slot = (ni * 2 + (c >> 3)) ^ (ql & 7);
          Pw[ql * 64 + slot * 8 + (c & 7)] = (short)f2bf(sa[mi][ni][r]);
        }
    #pragma unroll
    for (int ks = 0; ks < 2; ++ks) {
      short8_t aP[2], bV[4];
      #pragma unroll
      for (int mi = 0; mi < 2; ++mi) {
        int ql = mi * 16 + c;
        aP[mi] = *(const short8_t*)(Pw + ql * 64 + (((ks * 4 + g) ^ (ql & 7)) * 8));
      }
      #pragma unroll
      for (int nd = 0; nd < 4; ++nd) {
        int dr = nd * 16 + c;
        bV[nd] = *(const short8_t*)(Vp + dr * 64 + (((ks * 4 + g) ^ (dr & 7)) * 8));
      }
      #pragma unroll
      for (int mi = 0; mi < 2; ++mi)
        #pragma unroll
        for (int nd = 0; nd < 4; ++nd)
          oa[mi][nd] = __builtin_amdgcn_mfma_f32_16x16x32_bf16(aP[mi], bV[nd], oa[mi][nd], 0, 0, 0);
    }
    __builtin_amdgcn_sched_barrier(0);
  }

  #pragma unroll
  for (int mi = 0; mi < 2; ++mi)
    #pragma unroll
    for (int r = 0; r < 4; ++r) {
      size_t row = (size_t)b * SEQ + qt * 128 + wave * 32 + mi * 16 + g * 4 + r;
      const float* tvp = top_v + row * TOPK;
      const int*   tip = top_i + row * TOPK;
      float lg[TOPK];
      float mmax = m_[mi][r];
      #pragma unroll
      for (int j = 0; j < TOPK; ++j) { lg[j] = tvp[j]; mmax = fmaxf(mmax, lg[j]); }
      float f = __expf(m_[mi][r] - mmax);
      float l = l_[mi][r] * f;
      #pragma unroll
      for (int nd = 0; nd < 4; ++nd) oa[mi][nd][r] *= f;
      #pragma unroll
      for (int j = 0; j < TOPK; ++j) {
        float p = __expf(lg[j] - mmax);
        l += p;
        const float* mvp = MV + (size_t)tip[j] * E_DIM + h * HD + c;
        #pragma unroll
        for (int nd = 0; nd < 4; ++nd)
          oa[mi][nd][r] = fmaf(p, mvp[nd * 16], oa[mi][nd][r]);
      }
      float inv = 1.0f / l;
      #pragma unroll
      for (int nd = 0; nd < 4; ++nd)
        ctx[row * E_DIM + h * HD + nd * 16 + c] = f2bf(oa[mi][nd][r] * inv);
    }
}

// ---------------- launcher ----------------
extern "C" void kernel_launch(void* const* d_in, const int* in_sizes, int n_in,
                              void* d_out, int out_size, void* d_ws, size_t ws_size,
                              hipStream_t stream) {
  (void)in_sizes; (void)n_in; (void)out_size; (void)ws_size;
  const float* hidden = (const float*)d_in[0];
  const float* mkeys  = (const float*)d_in[1];
  const float* mvals  = (const float*)d_in[2];
  const float* Wq = (const float*)d_in[3];
  const float* bq = (const float*)d_in[4];
  const float* Wk = (const float*)d_in[5];
  const float* bk = (const float*)d_in[6];
  const float* Wv = (const float*)d_in[7];
  const float* bv = (const float*)d_in[8];
  const float* Wo = (const float*)d_in[9];
  const float* bo = (const float*)d_in[10];

  char* ws = (char*)d_ws;
  float* cand_v = (float*)ws;                                  ws += (size_t)R_TOT * NCHUNK * CANDS * 4;
  int*   cand_i = (int*)ws;                                    ws += (size_t)R_TOT * NCHUNK * CANDS * 4;
  int*   mid_i  = (int*)ws;                                    ws += (size_t)R_TOT * MIDK * 4;
  float* top_v  = (float*)ws;                                  ws += (size_t)R_TOT * TOPK * 4;
  int*   top_i  = (int*)ws;                                    ws += (size_t)R_TOT * TOPK * 4;
  float* rinvH  = (float*)ws;                                  ws += (size_t)R_TOT * 4;
  float* rinvK  = (float*)ws;                                  ws += (size_t)M_DIM * 4;
  unsigned short* Hn   = (unsigned short*)ws;                  ws += (size_t)R_TOT * E_DIM * 2;
  unsigned short* MKn  = (unsigned short*)ws;                  ws += (size_t)M_DIM * E_DIM * 2;
  unsigned short* hb   = (unsigned short*)ws;                  ws += (size_t)R_TOT * E_DIM * 2;
  unsigned short* wqb  = (unsigned short*)ws;                  ws += (size_t)E_DIM * E_DIM * 2;
  unsigned short* wkb  = (unsigned short*)ws;                  ws += (size_t)E_DIM * E_DIM * 2;
  unsigned short* wvb  = (unsigned short*)ws;                  ws += (size_t)E_DIM * E_DIM * 2;
  unsigned short* wob  = (unsigned short*)ws;                  ws += (size_t)E_DIM * E_DIM * 2;
  unsigned short* q_b  = (unsigned short*)ws;                  ws += (size_t)R_TOT * E_DIM * 2;
  unsigned short* k_b  = (unsigned short*)ws;                  ws += (size_t)R_TOT * E_DIM * 2;
  unsigned short* v_b  = (unsigned short*)ws;                  ws += (size_t)R_TOT * E_DIM * 2;
  unsigned short* vTb  = (unsigned short*)ws;                  ws += (size_t)R_TOT * E_DIM * 2;
  unsigned short* ctxb = (unsigned short*)ws;                  ws += (size_t)R_TOT * E_DIM * 2;

  norm_bf16_kernel<<<dim3(R_TOT), 256, 0, stream>>>(hidden, Hn, hb, rinvH);
  norm_bf16_kernel<<<dim3(M_DIM), 256, 0, stream>>>(mkeys, MKn, (unsigned short*)nullptr, rinvK);

  int n4w = E_DIM * E_DIM / 4;
  cast_bf16_kernel<<<dim3(n4w / 256), 256, 0, stream>>>(Wq, wqb, n4w);
  cast_bf16_kernel<<<dim3(n4w / 256), 256, 0, stream>>>(Wk, wkb, n4w);
  cast_bf16_kernel<<<dim3(n4w / 256), 256, 0, stream>>>(Wv, wvb, n4w);
  cast_bf16_kernel<<<dim3(n4w / 256), 256, 0, stream>>>(Wo, wob, n4w);

  mfma_gemm_qkv<<<dim3(R_TOT / 128, 3 * E_DIM / 128), 256, 0, stream>>>(
      hb, wqb, wkb, wvb, bq, bk, bv, q_b, k_b, v_b);

  vtrans_kernel<<<dim3(SEQ / 64, BATCH * H_NUM), 256, 0, stream>>>(v_b, vTb);

  sims_topk_kernel<<<dim3(R_TOT / 128, NCHUNK), 512, 0, stream>>>(Hn, MKn, cand_v, cand_i);
  merge_topk_kernel<<<dim3(R_TOT), 64, 0, stream>>>(cand_v, cand_i, mid_i);
  refine_kernel<<<dim3(R_TOT), 256, 0, stream>>>(hidden, mkeys, rinvH, rinvK, mid_i, top_v, top_i);

  flash_mfma_kernel<<<dim3(SEQ / 128, BATCH * H_NUM), 256, 0, stream>>>(
      q_b, k_b, vTb, mvals, top_v, top_i, ctxb);

  mfma_gemm_out<<<dim3(R_TOT / 128, E_DIM / 128), 256, 0, stream>>>(ctxb, wob, bo, (float*)d_out);
}

// Round 19
// 553.171 us; speedup vs baseline: 1.1296x; 1.1296x over previous
//
#include <hip/hip_runtime.h>
#include <math.h>

#define R_TOT 4096   // B*S
#define E_DIM 1024
#define M_DIM 16384
#define H_NUM 16
#define HD    64
#define SEQ   2048
#define BATCH 2
#define TOPK  8
#define MIDK  16
#define NCHUNK 16
#define SCHUNK 1024
#define CANDS  32

typedef __attribute__((ext_vector_type(8))) short short8_t;
typedef __attribute__((ext_vector_type(4))) float f32x4;

__device__ inline unsigned short f2bf(float x) {
  unsigned u = __float_as_uint(x);
  u = (u + 0x7fff + ((u >> 16) & 1)) >> 16;
  return (unsigned short)u;
}
__device__ inline float bf2f(unsigned short h) {
  return __uint_as_float(((unsigned)h) << 16);
}

#define GLDS16(gp, lp) __builtin_amdgcn_global_load_lds( \
    (const __attribute__((address_space(1))) void*)(gp), \
    (__attribute__((address_space(3))) void*)(lp), 16, 0, 0)

// ---------------- fused L2-normalize + bf16 cast (+ raw bf16 + rinv) ----------------
__global__ __launch_bounds__(256) void norm_bf16_kernel(const float* __restrict__ X,
                                                        unsigned short* __restrict__ Y,
                                                        unsigned short* __restrict__ Yraw,
                                                        float* __restrict__ rinv_out) {
  int row = blockIdx.x;
  int tid = threadIdx.x;
  const float4* xr = (const float4*)(X + (size_t)row * E_DIM);
  float4 v = xr[tid];
  float s = v.x*v.x + v.y*v.y + v.z*v.z + v.w*v.w;
  #pragma unroll
  for (int off = 32; off; off >>= 1) s += __shfl_down(s, off, 64);
  __shared__ float wsum[4];
  if ((tid & 63) == 0) wsum[tid >> 6] = s;
  __syncthreads();
  float tot = wsum[0] + wsum[1] + wsum[2] + wsum[3];
  float rinv = 1.0f / fmaxf(sqrtf(tot), 1e-12f);
  if (tid == 0) rinv_out[row] = rinv;
  ushort4 o;
  o.x = f2bf(v.x * rinv); o.y = f2bf(v.y * rinv);
  o.z = f2bf(v.z * rinv); o.w = f2bf(v.w * rinv);
  ((ushort4*)(Y + (size_t)row * E_DIM))[tid] = o;
  if (Yraw) {
    ushort4 o2;
    o2.x = f2bf(v.x); o2.y = f2bf(v.y); o2.z = f2bf(v.z); o2.w = f2bf(v.w);
    ((ushort4*)(Yraw + (size_t)row * E_DIM))[tid] = o2;
  }
}

// ---------------- fp32 -> bf16 cast ----------------
__global__ __launch_bounds__(256) void cast_bf16_kernel(const float* __restrict__ X,
                                                        unsigned short* __restrict__ Y, int n4) {
  int i = blockIdx.x * 256 + threadIdx.x;
  if (i < n4) {
    float4 v = ((const float4*)X)[i];
    ushort4 o;
    o.x = f2bf(v.x); o.y = f2bf(v.y); o.z = f2bf(v.z); o.w = f2bf(v.w);
    ((ushort4*)Y)[i] = o;
  }
}

// ---------------- pipelined MFMA 128x128 tile body (dbuf + counted vmcnt, 2 barriers/step) ----------------
// 64KB LDS -> 2 blocks/CU; R18 showed this beats quad-buffer/1-barrier at 128KB here.
template<int OUT_BF16>
__device__ __forceinline__ void gemm_tile_body_pipe(
    const unsigned short* __restrict__ Ab, const unsigned short* __restrict__ Bb,
    const float* __restrict__ bias, void* __restrict__ C, int N,
    int bm, int bn, char* pool) {
  int tid = threadIdx.x;
  int wave = tid >> 6, lane = tid & 63;
  int wr = wave >> 1, wc = wave & 1;
  int li8 = lane >> 3;
  int gslot = (lane & 7) ^ li8;

  auto STAGE = [&](int d, int k0) {   // 8 GLDS16 per thread -> 32KB tile
    #pragma unroll
    for (int s4 = 0; s4 < 8; ++s4) {
      int s = wave * 8 + s4;
      const unsigned short* gp;
      if (s < 16) {
        int r = s * 8 + li8;
        gp = Ab + (size_t)(bm + r) * E_DIM + k0 + gslot * 8;
      } else {
        int r = (s - 16) * 8 + li8;
        gp = Bb + (size_t)(bn + r) * E_DIM + k0 + gslot * 8;
      }
      GLDS16(gp, pool + d * 32768 + s * 1024);
    }
  };

  f32x4 acc[4][4];
  #pragma unroll
  for (int i = 0; i < 4; ++i)
    #pragma unroll
    for (int j = 0; j < 4; ++j)
      acc[i][j] = (f32x4){0.f, 0.f, 0.f, 0.f};

  STAGE(0, 0);

  for (int t = 0; t < E_DIM / 64; ++t) {
    int cur = t & 1;
    if (t + 1 < E_DIM / 64) {
      STAGE(1 - cur, (t + 1) * 64);
      asm volatile("s_waitcnt vmcnt(8)" ::: "memory");
    } else {
      asm volatile("s_waitcnt vmcnt(0)" ::: "memory");
    }
    __builtin_amdgcn_s_barrier();
    __builtin_amdgcn_sched_barrier(0);
    short* Ap = (short*)(pool + cur * 32768);
    short* Bp = (short*)(pool + cur * 32768 + 16384);
    #pragma unroll
    for (int ks = 0; ks < 2; ++ks) {
      short8_t af[4], bf[4];
      int kslot = ks * 4 + (lane >> 4);
      #pragma unroll
      for (int mi = 0; mi < 4; ++mi) {
        int r = wr * 64 + mi * 16 + (lane & 15);
        af[mi] = *(const short8_t*)(Ap + r * 64 + ((kslot ^ (r & 7)) * 8));
      }
      #pragma unroll
      for (int ni = 0; ni < 4; ++ni) {
        int r = wc * 64 + ni * 16 + (lane & 15);
        bf[ni] = *(const short8_t*)(Bp + r * 64 + ((kslot ^ (r & 7)) * 8));
      }
      #pragma unroll
      for (int mi = 0; mi < 4; ++mi)
        #pragma unroll
        for (int ni = 0; ni < 4; ++ni)
          acc[mi][ni] = __builtin_amdgcn_mfma_f32_16x16x32_bf16(af[mi], bf[ni], acc[mi][ni], 0, 0, 0);
    }
    __builtin_amdgcn_sched_barrier(0);
    __builtin_amdgcn_s_barrier();
  }
  #pragma unroll
  for (int mi = 0; mi < 4; ++mi) {
    #pragma unroll
    for (int ni = 0; ni < 4; ++ni) {
      int col = bn + wc * 64 + ni * 16 + (lane & 15);
      float bv = bias[col];
      #pragma unroll
      for (int r = 0; r < 4; ++r) {
        int row = bm + wr * 64 + mi * 16 + (lane >> 4) * 4 + r;
        float v = acc[mi][ni][r] + bv;
        if (OUT_BF16)
          ((unsigned short*)C)[(size_t)row * N + col] = f2bf(v);
        else
          ((float*)C)[(size_t)row * N + col] = v;
      }
    }
  }
}

// ---------------- output GEMM: C = A * Wo^T + bo (fp32 out) ----------------
__global__ __launch_bounds__(256) void mfma_gemm_out(
    const unsigned short* __restrict__ Ab, const unsigned short* __restrict__ Bb,
    const float* __restrict__ bias, float* __restrict__ C) {
  __shared__ __align__(16) char pool[65536];
  gemm_tile_body_pipe<0>(Ab, Bb, bias, C, E_DIM, blockIdx.x * 128, blockIdx.y * 128, pool);
}

// ---------------- batched QKV GEMM: grid.y covers N=3072 ----------------
__global__ __launch_bounds__(256) void mfma_gemm_qkv(
    const unsigned short* __restrict__ hb,
    const unsigned short* __restrict__ wq, const unsigned short* __restrict__ wk,
    const unsigned short* __restrict__ wv,
    const float* __restrict__ bq, const float* __restrict__ bk, const float* __restrict__ bv,
    unsigned short* __restrict__ q_b, unsigned short* __restrict__ k_b,
    unsigned short* __restrict__ v_b) {
  __shared__ __align__(16) char pool[65536];
  int bn_g = blockIdx.y * 128;
  int sel = bn_g >> 10;
  int bn = bn_g & 1023;
  const unsigned short* Bb = (sel == 0) ? wq : (sel == 1) ? wk : wv;
  const float* bias = (sel == 0) ? bq : (sel == 1) ? bk : bv;
  unsigned short* C = (sel == 0) ? q_b : (sel == 1) ? k_b : v_b;
  gemm_tile_body_pipe<1>(hb, Bb, bias, C, E_DIM, blockIdx.x * 128, bn, pool);
}

// ---------------- V transpose: vb[b][s][h][d] -> vT[b][h][d][s] (bf16) ----------------
__global__ __launch_bounds__(256) void vtrans_kernel(const unsigned short* __restrict__ vb,
                                                     unsigned short* __restrict__ vT) {
  int st = blockIdx.x;
  int bh = blockIdx.y;
  int b = bh >> 4, h = bh & 15;
  __shared__ short T[64][72];
  int tid = threadIdx.x;
  #pragma unroll
  for (int it = 0; it < 2; ++it) {
    int idx = tid + it * 256;
    int r = idx >> 3, sl = idx & 7;
    short8_t v = *(const short8_t*)(vb + ((size_t)(b * SEQ + st * 64 + r)) * E_DIM + h * HD + sl * 8);
    *(short8_t*)&T[r][sl * 8] = v;
  }
  __syncthreads();
  int d = tid >> 2, sp = (tid & 3) * 16;
  short8_t o0, o1;
  #pragma unroll
  for (int u = 0; u < 8; ++u) o0[u] = T[sp + u][d];
  #pragma unroll
  for (int u = 0; u < 8; ++u) o1[u] = T[sp + 8 + u][d];
  size_t base = ((size_t)bh * HD + d) * SEQ + st * 64 + sp;
  *(short8_t*)(vT + base) = o0;
  *(short8_t*)(vT + base + 8) = o1;
}

// ---------------- MFMA bf16 sims GEMM + fused top-8: 8-wave QUAD-buffer, ONE barrier/step ----------------
// Sims is pinned at 1 block/CU regardless; quad-buffer/1-barrier is a pure win here (R17).
#define NSTEP (SCHUNK / 128 * 16)   // 128 K-steps (8 subtiles x 16)

__global__ __launch_bounds__(512) void sims_topk_kernel(
    const unsigned short* __restrict__ Hn, const unsigned short* __restrict__ MKn,
    float* __restrict__ cand_v, int* __restrict__ cand_i) {
  __shared__ __align__(16) char pool[131072];   // buf0..buf3, 32KB each

  int bm = blockIdx.x * 128;
  int chunk = blockIdx.y;

  int tid = threadIdx.x;
  int wave = tid >> 6, lane = tid & 63;
  int wr = wave >> 2, wc = wave & 3;          // 2x4 wave grid, wave tile 64x32
  int srow = tid >> 2, sl = tid & 3;          // scan: 4 lanes/row, 32 cols each
  int li8 = lane >> 3;
  int gslot = (lane & 7) ^ li8;

  float tv[TOPK]; int ti[TOPK];
  #pragma unroll
  for (int u = 0; u < TOPK; ++u) { tv[u] = -INFINITY; ti[u] = 0; }

  auto STAGE = [&](int d, int t) {    // 4 GLDS16 per thread -> 32KB tile
    int sub = t >> 4;
    int k0 = (t & 15) * 64;
    int bn = chunk * SCHUNK + sub * 128;
    #pragma unroll
    for (int s4 = 0; s4 < 4; ++s4) {
      int s = wave * 4 + s4;
      const unsigned short* gp;
      if (s < 16) {
        int r = s * 8 + li8;
        gp = Hn + (size_t)(bm + r) * E_DIM + k0 + gslot * 8;
      } else {
        int r = (s - 16) * 8 + li8;
        gp = MKn + (size_t)(bn + r) * E_DIM + k0 + gslot * 8;
      }
      GLDS16(gp, pool + d * 32768 + s * 1024);
    }
  };

  f32x4 acc[4][2];
  #pragma unroll
  for (int i = 0; i < 4; ++i)
    #pragma unroll
    for (int j = 0; j < 2; ++j)
      acc[i][j] = (f32x4){0.f, 0.f, 0.f, 0.f};

  STAGE(0, 0);
  STAGE(1, 1);

  for (int t = 0; t < NSTEP; ++t) {
    int cur = t & 3;
    if (t + 2 < NSTEP) {
      STAGE((t + 2) & 3, t + 2);
      asm volatile("s_waitcnt vmcnt(8)" ::: "memory");   // tile-t's 4 landed (t+1,t+2 in flight)
    } else if (t + 1 < NSTEP) {
      asm volatile("s_waitcnt vmcnt(4)" ::: "memory");
    } else {
      asm volatile("s_waitcnt vmcnt(0)" ::: "memory");
    }
    __builtin_amdgcn_s_barrier();          // single barrier per step
    __builtin_amdgcn_sched_barrier(0);

    short* Ap = (short*)(pool + cur * 32768);
    short* Bp = (short*)(pool + cur * 32768 + 16384);
    #pragma unroll
    for (int ks = 0; ks < 2; ++ks) {
      short8_t af[4], bf[2];
      int kslot = ks * 4 + (lane >> 4);
      #pragma unroll
      for (int mi = 0; mi < 4; ++mi) {
        int r = wr * 64 + mi * 16 + (lane & 15);
        af[mi] = *(const short8_t*)(Ap + r * 64 + ((kslot ^ (r & 7)) * 8));
      }
      #pragma unroll
      for (int ni = 0; ni < 2; ++ni) {
        int r = wc * 32 + ni * 16 + (lane & 15);
        bf[ni] = *(const short8_t*)(Bp + r * 64 + ((kslot ^ (r & 7)) * 8));
      }
      #pragma unroll
      for (int mi = 0; mi < 4; ++mi)
        #pragma unroll
        for (int ni = 0; ni < 2; ++ni)
          acc[mi][ni] = __builtin_amdgcn_mfma_f32_16x16x32_bf16(af[mi], bf[ni], acc[mi][ni], 0, 0, 0);
    }
    __builtin_amdgcn_sched_barrier(0);

    if ((t & 15) == 15) {
      __builtin_amdgcn_s_barrier();   // all waves done reading buf[cur] before scan overwrites
      short* Sp = (short*)(pool + cur * 32768);
      int bn = chunk * SCHUNK + (t >> 4) * 128;
      #pragma unroll
      for (int mi = 0; mi < 4; ++mi) {
        #pragma unroll
        for (int ni = 0; ni < 2; ++ni) {
          int scol = wc * 32 + ni * 16 + (lane & 15);
          #pragma unroll
          for (int r = 0; r < 4; ++r) {
            int srw = wr * 64 + mi * 16 + (lane >> 4) * 4 + r;
            Sp[srw * 128 + (scol ^ ((srw & 15) << 3))] = (short)f2bf(acc[mi][ni][r]);
          }
          acc[mi][ni] = (f32x4){0.f, 0.f, 0.f, 0.f};
        }
      }
      __syncthreads();
      #pragma unroll
      for (int u4 = 0; u4 < 8; ++u4) {
        int col = sl * 32 + u4 * 4;
        const short* p = Sp + srow * 128 + (col ^ ((srow & 15) << 3));
        short4 v4 = *(const short4*)p;
        short vv[4] = {v4.x, v4.y, v4.z, v4.w};
        #pragma unroll
        for (int j = 0; j < 4; ++j) {
          float v = bf2f((unsigned short)vv[j]);
          if (v > tv[0]) {
            int idx = bn + col + j;
            int p_ = 0;
            #pragma unroll
            for (int q = 1; q < TOPK; ++q)
              if (v > tv[q]) { tv[q-1] = tv[q]; ti[q-1] = ti[q]; p_ = q; }
            tv[p_] = v; ti[p_] = idx;
          }
        }
      }
      __syncthreads();   // scan done before buf[cur] restaged (at step t+2)
    }
  }
  size_t base = (((size_t)(bm + srow)) * NCHUNK + chunk) * CANDS + sl * TOPK;
  #pragma unroll
  for (int u = 0; u < TOPK; ++u) { cand_v[base + u] = tv[u]; cand_i[base + u] = ti[u]; }
}

// ---------------- merge 512 candidates/row -> top-16 (bf16-order) ----------------
__global__ __launch_bounds__(64) void merge_topk_kernel(
    const float* __restrict__ cand_v, const int* __restrict__ cand_i,
    int* __restrict__ mid_i) {
  int row = blockIdx.x;
  int lane = threadIdx.x;
  size_t base = (size_t)row * (NCHUNK * CANDS);
  float v[8]; int id[8];
  #pragma unroll
  for (int u = 0; u < 8; ++u) {
    v[u]  = cand_v[base + lane*8 + u];
    id[u] = cand_i[base + lane*8 + u];
  }
  for (int t = 0; t < MIDK; ++t) {
    float bvv = v[0]; int bu = 0;
    #pragma unroll
    for (int u = 1; u < 8; ++u) if (v[u] > bvv) { bvv = v[u]; bu = u; }
    float mv = bvv; int ml = lane;
    #pragma unroll
    for (int off = 32; off; off >>= 1) {
      float ov = __shfl_down(mv, off, 64);
      int   ol = __shfl_down(ml, off, 64);
      if (ov > mv) { mv = ov; ml = ol; }
    }
    ml = __shfl(ml, 0, 64);
    if (lane == ml) {
      mid_i[(size_t)row * MIDK + t] = id[bu];
      v[bu] = -INFINITY;
    }
  }
}

// ---------------- exact fp32 refine: 16 candidates -> true top-8 ----------------
__global__ __launch_bounds__(256) void refine_kernel(
    const float* __restrict__ hidden, const float* __restrict__ mkeys,
    const float* __restrict__ rinvH, const float* __restrict__ rinvK,
    const int* __restrict__ mid_i,
    float* __restrict__ top_v, int* __restrict__ top_i) {
  int row = blockIdx.x;
  int tid = threadIdx.x;
  int wave = tid >> 6, lane = tid & 63;
  __shared__ float hrow[E_DIM];
  __shared__ float rv[MIDK];
  __shared__ int   ri[MIDK];
  ((float4*)hrow)[tid] = ((const float4*)(hidden + (size_t)row * E_DIM))[tid];
  __syncthreads();
  float rh = rinvH[row];
  for (int c = wave; c < MIDK; c += 4) {
    int idx = mid_i[(size_t)row * MIDK + c];
    const float* kp = mkeys + (size_t)idx * E_DIM;
    float s = 0.f;
    #pragma unroll
    for (int rr = 0; rr < 4; ++rr) {
      float4 kv = *(const float4*)(kp + rr * 256 + lane * 4);
      float4 hv = *(const float4*)(hrow + rr * 256 + lane * 4);
      s += hv.x*kv.x + hv.y*kv.y + hv.z*kv.z + hv.w*kv.w;
    }
    #pragma unroll
    for (int off = 32; off; off >>= 1) s += __shfl_down(s, off, 64);
    if (lane == 0) { rv[c] = s * rh * rinvK[idx]; ri[c] = idx; }
  }
  __syncthreads();
  if (tid == 0) {
    bool used[MIDK] = {};
    #pragma unroll
    for (int t = 0; t < TOPK; ++t) {
      float best = -INFINITY; int bi = -1; int bidx = 0x7fffffff;
      for (int c = 0; c < MIDK; ++c) {
        if (used[c]) continue;
        if (rv[c] > best || (rv[c] == best && ri[c] < bidx)) {
          best = rv[c]; bi = c; bidx = ri[c];
        }
      }
      used[bi] = true;
      top_v[(size_t)row * TOPK + t] = best;
      top_i[(size_t)row * TOPK + t] = bidx;
    }
  }
}

// ---------------- MFMA flash attention: Q-in-LDS + dbuf K/V + counted vmcnt (R17 config) ----------------
__global__ __launch_bounds__(256) void flash_mfma_kernel(
    const unsigned short* __restrict__ qb, const unsigned short* __restrict__ kb,
    const unsigned short* __restrict__ vT, const float* __restrict__ MV,
    const float* __restrict__ top_v, const int* __restrict__ top_i,
    unsigned short* __restrict__ ctx) {
  __shared__ __align__(16) char pool[65536];   // Qs 16K | buf0 16K | buf1 16K | P 4x4K
  short* Qs = (short*)pool;
  int qt = blockIdx.x;
  int bh = blockIdx.y;
  int b = bh >> 4, h = bh & 15;
  int tid = threadIdx.x;
  int wave = tid >> 6, lane = tid & 63;
  int g = lane >> 4, c = lane & 15;
  int li8 = lane >> 3;
  int gslot = (lane & 7) ^ li8;
  short* Pw = (short*)(pool + 49152 + wave * 4096);
  const float scale = 0.125f;

  auto STAGEKV = [&](int d, int kv0) {
    #pragma unroll
    for (int j = 0; j < 4; ++j) {
      int s = wave * 4 + j;
      const unsigned short* gp;
      if (s < 8) {
        int r = s * 8 + li8;
        gp = kb + ((size_t)(b * SEQ + kv0 + r)) * E_DIM + h * HD + gslot * 8;
      } else {
        int dd = (s - 8) * 8 + li8;
        gp = vT + ((size_t)(bh * HD + dd)) * SEQ + kv0 + gslot * 8;
      }
      GLDS16(gp, pool + 16384 + d * 16384 + s * 1024);
    }
  };

  #pragma unroll
  for (int j = 0; j < 4; ++j) {
    int s = wave * 4 + j;
    int r = s * 8 + li8;
    const unsigned short* gp = qb + ((size_t)(b * SEQ) + qt * 128 + r) * E_DIM + h * HD + gslot * 8;
    GLDS16(gp, pool + s * 1024);
  }
  STAGEKV(0, 0);
  __syncthreads();

  short8_t aQ[2][2];
  #pragma unroll
  for (int mi = 0; mi < 2; ++mi)
    #pragma unroll
    for (int ks = 0; ks < 2; ++ks) {
      int r = wave * 32 + mi * 16 + c;
      int slot = ks * 4 + g;
      aQ[mi][ks] = *(const short8_t*)(Qs + r * 64 + ((slot ^ (r & 7)) * 8));
    }

  f32x4 oa[2][4];
  #pragma unroll
  for (int mi = 0; mi < 2; ++mi)
    #pragma unroll
    for (int nd = 0; nd < 4; ++nd)
      oa[mi][nd] = (f32x4){0.f, 0.f, 0.f, 0.f};
  float m_[2][4], l_[2][4];
  #pragma unroll
  for (int mi = 0; mi < 2; ++mi)
    #pragma unroll
    for (int r = 0; r < 4; ++r) { m_[mi][r] = -INFINITY; l_[mi][r] = 0.f; }

  for (int kt = 0; kt < SEQ / 64; ++kt) {
    int cur = kt & 1;
    if (kt + 1 < SEQ / 64) {
      STAGEKV(1 - cur, (kt + 1) * 64);
      asm volatile("s_waitcnt vmcnt(4)" ::: "memory");
    } else {
      asm volatile("s_waitcnt vmcnt(0)" ::: "memory");
    }
    __builtin_amdgcn_s_barrier();
    __builtin_amdgcn_sched_barrier(0);
    short* Kp = (short*)(pool + 16384 + cur * 16384);
    short* Vp = (short*)(pool + 16384 + cur * 16384 + 8192);

    f32x4 sa[2][4];
    #pragma unroll
    for (int mi = 0; mi < 2; ++mi)
      #pragma unroll
      for (int ni = 0; ni < 4; ++ni)
        sa[mi][ni] = (f32x4){0.f, 0.f, 0.f, 0.f};
    #pragma unroll
    for (int ks = 0; ks < 2; ++ks) {
      short8_t bK[4];
      #pragma unroll
      for (int ni = 0; ni < 4; ++ni) {
        int r = ni * 16 + c;
        bK[ni] = *(const short8_t*)(Kp + r * 64 + (((ks * 4 + g) ^ (r & 7)) * 8));
      }
      #pragma unroll
      for (int mi = 0; mi < 2; ++mi)
        #pragma unroll
        for (int ni = 0; ni < 4; ++ni)
          sa[mi][ni] = __builtin_amdgcn_mfma_f32_16x16x32_bf16(aQ[mi][ks], bK[ni], sa[mi][ni], 0, 0, 0);
    }
    #pragma unroll
    for (int mi = 0; mi < 2; ++mi)
      #pragma unroll
      for (int ni = 0; ni < 4; ++ni)
        #pragma unroll
        for (int r = 0; r < 4; ++r)
          sa[mi][ni][r] *= scale;
    float fsc[2][4];
    #pragma unroll
    for (int mi = 0; mi < 2; ++mi)
      #pragma unroll
      for (int r = 0; r < 4; ++r) {
        float m0 = fmaxf(fmaxf(sa[mi][0][r], sa[mi][1][r]), fmaxf(sa[mi][2][r], sa[mi][3][r]));
        #pragma unroll
        for (int off = 1; off < 16; off <<= 1) m0 = fmaxf(m0, __shfl_xor(m0, off, 64));
        float mn = fmaxf(m_[mi][r], m0);
        fsc[mi][r] = __expf(m_[mi][r] - mn);
        m_[mi][r] = mn;
      }
    #pragma unroll
    for (int mi = 0; mi < 2; ++mi)
      #pragma unroll
      for (int nd = 0; nd < 4; ++nd)
        #pragma unroll
        for (int r = 0; r < 4; ++r)
          oa[mi][nd][r] *= fsc[mi][r];
    #pragma unroll
    for (int mi = 0; mi < 2; ++mi)
      #pragma unroll
      for (int r = 0; r < 4; ++r) {
        float ps = 0.f;
        #pragma unroll
        for (int ni = 0; ni < 4; ++ni) {
          float p = __expf(sa[mi][ni][r] - m_[mi][r]);
          sa[mi][ni][r] = p;
          ps += p;
        }
        #pragma unroll
        for (int off = 1; off < 16; off <<= 1) ps += __shfl_xor(ps, off, 64);
        l_[mi][r] = l_[mi][r] * fsc[mi][r] + ps;
      }
    #pragma unroll
    for (int mi = 0; mi < 2; ++mi)
      #pragma unroll
      for (int ni = 0; ni < 4; ++ni)
        #pragma unroll
        for (int r = 0; r < 4; ++r) {
          int ql = mi * 16 + g * 4 + r;
          int slot = (ni * 2 + (c >> 3)) ^ (ql & 7);
          Pw[ql * 64 + slot * 8 + (c & 7)] = (short)f2bf(sa[mi][ni][r]);
        }
    #pragma unroll
    for (int ks = 0; ks < 2; ++ks) {
      short8_t aP[2], bV[4];
      #pragma unroll
      for (int mi = 0; mi < 2; ++mi) {
        int ql = mi * 16 + c;
        aP[mi] = *(const short8_t*)(Pw + ql * 64 + (((ks * 4 + g) ^ (ql & 7)) * 8));
      }
      #pragma unroll
      for (int nd = 0; nd < 4; ++nd) {
        int dr = nd * 16 + c;
        bV[nd] = *(const short8_t*)(Vp + dr * 64 + (((ks * 4 + g) ^ (dr & 7)) * 8));
      }
      #pragma unroll
      for (int mi = 0; mi < 2; ++mi)
        #pragma unroll
        for (int nd = 0; nd < 4; ++nd)
          oa[mi][nd] = __builtin_amdgcn_mfma_f32_16x16x32_bf16(aP[mi], bV[nd], oa[mi][nd], 0, 0, 0);
    }
    __builtin_amdgcn_sched_barrier(0);
    __builtin_amdgcn_s_barrier();
  }

  #pragma unroll
  for (int mi = 0; mi < 2; ++mi)
    #pragma unroll
    for (int r = 0; r < 4; ++r) {
      size_t row = (size_t)b * SEQ + qt * 128 + wave * 32 + mi * 16 + g * 4 + r;
      const float* tvp = top_v + row * TOPK;
      const int*   tip = top_i + row * TOPK;
      float lg[TOPK];
      float mmax = m_[mi][r];
      #pragma unroll
      for (int j = 0; j < TOPK; ++j) { lg[j] = tvp[j]; mmax = fmaxf(mmax, lg[j]); }
      float f = __expf(m_[mi][r] - mmax);
      float l = l_[mi][r] * f;
      #pragma unroll
      for (int nd = 0; nd < 4; ++nd) oa[mi][nd][r] *= f;
      #pragma unroll
      for (int j = 0; j < TOPK; ++j) {
        float p = __expf(lg[j] - mmax);
        l += p;
        const float* mvp = MV + (size_t)tip[j] * E_DIM + h * HD + c;
        #pragma unroll
        for (int nd = 0; nd < 4; ++nd)
          oa[mi][nd][r] = fmaf(p, mvp[nd * 16], oa[mi][nd][r]);
      }
      float inv = 1.0f / l;
      #pragma unroll
      for (int nd = 0; nd < 4; ++nd)
        ctx[row * E_DIM + h * HD + nd * 16 + c] = f2bf(oa[mi][nd][r] * inv);
    }
}

// ---------------- launcher ----------------
extern "C" void kernel_launch(void* const* d_in, const int* in_sizes, int n_in,
                              void* d_out, int out_size, void* d_ws, size_t ws_size,
                              hipStream_t stream) {
  (void)in_sizes; (void)n_in; (void)out_size; (void)ws_size;
  const float* hidden = (const float*)d_in[0];
  const float* mkeys  = (const float*)d_in[1];
  const float* mvals  = (const float*)d_in[2];
  const float* Wq = (const float*)d_in[3];
  const float* bq = (const float*)d_in[4];
  const float* Wk = (const float*)d_in[5];
  const float* bk = (const float*)d_in[6];
  const float* Wv = (const float*)d_in[7];
  const float* bv = (const float*)d_in[8];
  const float* Wo = (const float*)d_in[9];
  const float* bo = (const float*)d_in[10];

  char* ws = (char*)d_ws;
  float* cand_v = (float*)ws;                                  ws += (size_t)R_TOT * NCHUNK * CANDS * 4;
  int*   cand_i = (int*)ws;                                    ws += (size_t)R_TOT * NCHUNK * CANDS * 4;
  int*   mid_i  = (int*)ws;                                    ws += (size_t)R_TOT * MIDK * 4;
  float* top_v  = (float*)ws;                                  ws += (size_t)R_TOT * TOPK * 4;
  int*   top_i  = (int*)ws;                                    ws += (size_t)R_TOT * TOPK * 4;
  float* rinvH  = (float*)ws;                                  ws += (size_t)R_TOT * 4;
  float* rinvK  = (float*)ws;                                  ws += (size_t)M_DIM * 4;
  unsigned short* Hn   = (unsigned short*)ws;                  ws += (size_t)R_TOT * E_DIM * 2;
  unsigned short* MKn  = (unsigned short*)ws;                  ws += (size_t)M_DIM * E_DIM * 2;
  unsigned short* hb   = (unsigned short*)ws;                  ws += (size_t)R_TOT * E_DIM * 2;
  unsigned short* wqb  = (unsigned short*)ws;                  ws += (size_t)E_DIM * E_DIM * 2;
  unsigned short* wkb  = (unsigned short*)ws;                  ws += (size_t)E_DIM * E_DIM * 2;
  unsigned short* wvb  = (unsigned short*)ws;                  ws += (size_t)E_DIM * E_DIM * 2;
  unsigned short* wob  = (unsigned short*)ws;                  ws += (size_t)E_DIM * E_DIM * 2;
  unsigned short* q_b  = (unsigned short*)ws;                  ws += (size_t)R_TOT * E_DIM * 2;
  unsigned short* k_b  = (unsigned short*)ws;                  ws += (size_t)R_TOT * E_DIM * 2;
  unsigned short* v_b  = (unsigned short*)ws;                  ws += (size_t)R_TOT * E_DIM * 2;
  unsigned short* vTb  = (unsigned short*)ws;                  ws += (size_t)R_TOT * E_DIM * 2;
  unsigned short* ctxb = (unsigned short*)ws;                  ws += (size_t)R_TOT * E_DIM * 2;

  norm_bf16_kernel<<<dim3(R_TOT), 256, 0, stream>>>(hidden, Hn, hb, rinvH);
  norm_bf16_kernel<<<dim3(M_DIM), 256, 0, stream>>>(mkeys, MKn, (unsigned short*)nullptr, rinvK);

  int n4w = E_DIM * E_DIM / 4;
  cast_bf16_kernel<<<dim3(n4w / 256), 256, 0, stream>>>(Wq, wqb, n4w);
  cast_bf16_kernel<<<dim3(n4w / 256), 256, 0, stream>>>(Wk, wkb, n4w);
  cast_bf16_kernel<<<dim3(n4w / 256), 256, 0, stream>>>(Wv, wvb, n4w);
  cast_bf16_kernel<<<dim3(n4w / 256), 256, 0, stream>>>(Wo, wob, n4w);

  mfma_gemm_qkv<<<dim3(R_TOT / 128, 3 * E_DIM / 128), 256, 0, stream>>>(
      hb, wqb, wkb, wvb, bq, bk, bv, q_b, k_b, v_b);

  vtrans_kernel<<<dim3(SEQ / 64, BATCH * H_NUM), 256, 0, stream>>>(v_b, vTb);

  sims_topk_kernel<<<dim3(R_TOT / 128, NCHUNK), 512, 0, stream>>>(Hn, MKn, cand_v, cand_i);
  merge_topk_kernel<<<dim3(R_TOT), 64, 0, stream>>>(cand_v, cand_i, mid_i);
  refine_kernel<<<dim3(R_TOT), 256, 0, stream>>>(hidden, mkeys, rinvH, rinvK, mid_i, top_v, top_i);

  flash_mfma_kernel<<<dim3(SEQ / 128, BATCH * H_NUM), 256, 0, stream>>>(
      q_b, k_b, vTb, mvals, top_v, top_i, ctxb);

  mfma_gemm_out<<<dim3(R_TOT / 128, E_DIM / 128), 256, 0, stream>>>(ctxb, wob, bo, (float*)d_out);
}

// Round 20
// 543.150 us; speedup vs baseline: 1.1504x; 1.0185x over previous
//
#include <hip/hip_runtime.h>
#include <math.h>

#define R_TOT 4096   // B*S
#define E_DIM 1024
#define M_DIM 16384
#define H_NUM 16
#define HD    64
#define SEQ   2048
#define BATCH 2
#define TOPK  8
#define MIDK  16
#define NCHUNK 16
#define SCHUNK 1024
#define CANDS  32

typedef __attribute__((ext_vector_type(8))) short short8_t;
typedef __attribute__((ext_vector_type(4))) float f32x4;

__device__ inline unsigned short f2bf(float x) {
  unsigned u = __float_as_uint(x);
  u = (u + 0x7fff + ((u >> 16) & 1)) >> 16;
  return (unsigned short)u;
}
__device__ inline float bf2f(unsigned short h) {
  return __uint_as_float(((unsigned)h) << 16);
}

#define GLDS16(gp, lp) __builtin_amdgcn_global_load_lds( \
    (const __attribute__((address_space(1))) void*)(gp), \
    (__attribute__((address_space(3))) void*)(lp), 16, 0, 0)

// ---------------- fused L2-normalize + bf16 cast: hidden AND mkeys in one launch ----------------
__global__ __launch_bounds__(256) void norm_all_kernel(
    const float* __restrict__ hidden, const float* __restrict__ mkeys,
    unsigned short* __restrict__ Hn, unsigned short* __restrict__ MKn,
    unsigned short* __restrict__ hb,
    float* __restrict__ rinvH, float* __restrict__ rinvK) {
  int rb = blockIdx.x;
  int tid = threadIdx.x;
  const float* X;
  unsigned short* Y;
  unsigned short* Yraw;
  float* rout;
  int row;
  if (rb < R_TOT) {
    row = rb; X = hidden + (size_t)row * E_DIM;
    Y = Hn + (size_t)row * E_DIM; Yraw = hb + (size_t)row * E_DIM; rout = rinvH + row;
  } else {
    row = rb - R_TOT; X = mkeys + (size_t)row * E_DIM;
    Y = MKn + (size_t)row * E_DIM; Yraw = nullptr; rout = rinvK + row;
  }
  float4 v = ((const float4*)X)[tid];
  float s = v.x*v.x + v.y*v.y + v.z*v.z + v.w*v.w;
  #pragma unroll
  for (int off = 32; off; off >>= 1) s += __shfl_down(s, off, 64);
  __shared__ float wsum[4];
  if ((tid & 63) == 0) wsum[tid >> 6] = s;
  __syncthreads();
  float tot = wsum[0] + wsum[1] + wsum[2] + wsum[3];
  float rinv = 1.0f / fmaxf(sqrtf(tot), 1e-12f);
  if (tid == 0) *rout = rinv;
  ushort4 o;
  o.x = f2bf(v.x * rinv); o.y = f2bf(v.y * rinv);
  o.z = f2bf(v.z * rinv); o.w = f2bf(v.w * rinv);
  ((ushort4*)Y)[tid] = o;
  if (Yraw) {
    ushort4 o2;
    o2.x = f2bf(v.x); o2.y = f2bf(v.y); o2.z = f2bf(v.z); o2.w = f2bf(v.w);
    ((ushort4*)Yraw)[tid] = o2;
  }
}

// ---------------- fused fp32 -> bf16 cast for all four weight matrices ----------------
__global__ __launch_bounds__(256) void cast_all_kernel(
    const float* __restrict__ W0, const float* __restrict__ W1,
    const float* __restrict__ W2, const float* __restrict__ W3,
    unsigned short* __restrict__ Y0, unsigned short* __restrict__ Y1,
    unsigned short* __restrict__ Y2, unsigned short* __restrict__ Y3, int n4) {
  int sel = blockIdx.y;
  const float* X = (sel == 0) ? W0 : (sel == 1) ? W1 : (sel == 2) ? W2 : W3;
  unsigned short* Y = (sel == 0) ? Y0 : (sel == 1) ? Y1 : (sel == 2) ? Y2 : Y3;
  int i = blockIdx.x * 256 + threadIdx.x;
  if (i < n4) {
    float4 v = ((const float4*)X)[i];
    ushort4 o;
    o.x = f2bf(v.x); o.y = f2bf(v.y); o.z = f2bf(v.z); o.w = f2bf(v.w);
    ((ushort4*)Y)[i] = o;
  }
}

// ---------------- pipelined MFMA 128x128 tile body (dbuf + counted vmcnt, 2 barriers/step) ----------------
template<int OUT_BF16>
__device__ __forceinline__ void gemm_tile_body_pipe(
    const unsigned short* __restrict__ Ab, const unsigned short* __restrict__ Bb,
    const float* __restrict__ bias, void* __restrict__ C, int N,
    int bm, int bn, char* pool) {
  int tid = threadIdx.x;
  int wave = tid >> 6, lane = tid & 63;
  int wr = wave >> 1, wc = wave & 1;
  int li8 = lane >> 3;
  int gslot = (lane & 7) ^ li8;

  auto STAGE = [&](int d, int k0) {   // 8 GLDS16 per thread -> 32KB tile
    #pragma unroll
    for (int s4 = 0; s4 < 8; ++s4) {
      int s = wave * 8 + s4;
      const unsigned short* gp;
      if (s < 16) {
        int r = s * 8 + li8;
        gp = Ab + (size_t)(bm + r) * E_DIM + k0 + gslot * 8;
      } else {
        int r = (s - 16) * 8 + li8;
        gp = Bb + (size_t)(bn + r) * E_DIM + k0 + gslot * 8;
      }
      GLDS16(gp, pool + d * 32768 + s * 1024);
    }
  };

  f32x4 acc[4][4];
  #pragma unroll
  for (int i = 0; i < 4; ++i)
    #pragma unroll
    for (int j = 0; j < 4; ++j)
      acc[i][j] = (f32x4){0.f, 0.f, 0.f, 0.f};

  STAGE(0, 0);

  for (int t = 0; t < E_DIM / 64; ++t) {
    int cur = t & 1;
    if (t + 1 < E_DIM / 64) {
      STAGE(1 - cur, (t + 1) * 64);
      asm volatile("s_waitcnt vmcnt(8)" ::: "memory");
    } else {
      asm volatile("s_waitcnt vmcnt(0)" ::: "memory");
    }
    __builtin_amdgcn_s_barrier();
    __builtin_amdgcn_sched_barrier(0);
    short* Ap = (short*)(pool + cur * 32768);
    short* Bp = (short*)(pool + cur * 32768 + 16384);
    #pragma unroll
    for (int ks = 0; ks < 2; ++ks) {
      short8_t af[4], bf[4];
      int kslot = ks * 4 + (lane >> 4);
      #pragma unroll
      for (int mi = 0; mi < 4; ++mi) {
        int r = wr * 64 + mi * 16 + (lane & 15);
        af[mi] = *(const short8_t*)(Ap + r * 64 + ((kslot ^ (r & 7)) * 8));
      }
      #pragma unroll
      for (int ni = 0; ni < 4; ++ni) {
        int r = wc * 64 + ni * 16 + (lane & 15);
        bf[ni] = *(const short8_t*)(Bp + r * 64 + ((kslot ^ (r & 7)) * 8));
      }
      #pragma unroll
      for (int mi = 0; mi < 4; ++mi)
        #pragma unroll
        for (int ni = 0; ni < 4; ++ni)
          acc[mi][ni] = __builtin_amdgcn_mfma_f32_16x16x32_bf16(af[mi], bf[ni], acc[mi][ni], 0, 0, 0);
    }
    __builtin_amdgcn_sched_barrier(0);
    __builtin_amdgcn_s_barrier();
  }
  #pragma unroll
  for (int mi = 0; mi < 4; ++mi) {
    #pragma unroll
    for (int ni = 0; ni < 4; ++ni) {
      int col = bn + wc * 64 + ni * 16 + (lane & 15);
      float bv = bias[col];
      #pragma unroll
      for (int r = 0; r < 4; ++r) {
        int row = bm + wr * 64 + mi * 16 + (lane >> 4) * 4 + r;
        float v = acc[mi][ni][r] + bv;
        if (OUT_BF16)
          ((unsigned short*)C)[(size_t)row * N + col] = f2bf(v);
        else
          ((float*)C)[(size_t)row * N + col] = v;
      }
    }
  }
}

// ---------------- output GEMM: C = A * Wo^T + bo (fp32 out) ----------------
__global__ __launch_bounds__(256) void mfma_gemm_out(
    const unsigned short* __restrict__ Ab, const unsigned short* __restrict__ Bb,
    const float* __restrict__ bias, float* __restrict__ C) {
  __shared__ __align__(16) char pool[65536];
  gemm_tile_body_pipe<0>(Ab, Bb, bias, C, E_DIM, blockIdx.x * 128, blockIdx.y * 128, pool);
}

// ---------------- batched QKV GEMM: grid.y covers N=3072 ----------------
__global__ __launch_bounds__(256) void mfma_gemm_qkv(
    const unsigned short* __restrict__ hb,
    const unsigned short* __restrict__ wq, const unsigned short* __restrict__ wk,
    const unsigned short* __restrict__ wv,
    const float* __restrict__ bq, const float* __restrict__ bk, const float* __restrict__ bv,
    unsigned short* __restrict__ q_b, unsigned short* __restrict__ k_b,
    unsigned short* __restrict__ v_b) {
  __shared__ __align__(16) char pool[65536];
  int bn_g = blockIdx.y * 128;
  int sel = bn_g >> 10;
  int bn = bn_g & 1023;
  const unsigned short* Bb = (sel == 0) ? wq : (sel == 1) ? wk : wv;
  const float* bias = (sel == 0) ? bq : (sel == 1) ? bk : bv;
  unsigned short* C = (sel == 0) ? q_b : (sel == 1) ? k_b : v_b;
  gemm_tile_body_pipe<1>(hb, Bb, bias, C, E_DIM, blockIdx.x * 128, bn, pool);
}

// ---------------- V transpose: vb[b][s][h][d] -> vT[b][h][d][s] (bf16) ----------------
__global__ __launch_bounds__(256) void vtrans_kernel(const unsigned short* __restrict__ vb,
                                                     unsigned short* __restrict__ vT) {
  int st = blockIdx.x;
  int bh = blockIdx.y;
  int b = bh >> 4, h = bh & 15;
  __shared__ short T[64][72];
  int tid = threadIdx.x;
  #pragma unroll
  for (int it = 0; it < 2; ++it) {
    int idx = tid + it * 256;
    int r = idx >> 3, sl = idx & 7;
    short8_t v = *(const short8_t*)(vb + ((size_t)(b * SEQ + st * 64 + r)) * E_DIM + h * HD + sl * 8);
    *(short8_t*)&T[r][sl * 8] = v;
  }
  __syncthreads();
  int d = tid >> 2, sp = (tid & 3) * 16;
  short8_t o0, o1;
  #pragma unroll
  for (int u = 0; u < 8; ++u) o0[u] = T[sp + u][d];
  #pragma unroll
  for (int u = 0; u < 8; ++u) o1[u] = T[sp + 8 + u][d];
  size_t base = ((size_t)bh * HD + d) * SEQ + st * 64 + sp;
  *(short8_t*)(vT + base) = o0;
  *(short8_t*)(vT + base + 8) = o1;
}

// ---------------- MFMA bf16 sims GEMM + fused top-8: 8-wave QUAD-buffer, ONE barrier/step ----------------
#define NSTEP (SCHUNK / 128 * 16)   // 128 K-steps (8 subtiles x 16)

__global__ __launch_bounds__(512) void sims_topk_kernel(
    const unsigned short* __restrict__ Hn, const unsigned short* __restrict__ MKn,
    float* __restrict__ cand_v, int* __restrict__ cand_i) {
  __shared__ __align__(16) char pool[131072];   // buf0..buf3, 32KB each

  int bm = blockIdx.x * 128;
  int chunk = blockIdx.y;

  int tid = threadIdx.x;
  int wave = tid >> 6, lane = tid & 63;
  int wr = wave >> 2, wc = wave & 3;          // 2x4 wave grid, wave tile 64x32
  int srow = tid >> 2, sl = tid & 3;          // scan: 4 lanes/row, 32 cols each
  int li8 = lane >> 3;
  int gslot = (lane & 7) ^ li8;

  float tv[TOPK]; int ti[TOPK];
  #pragma unroll
  for (int u = 0; u < TOPK; ++u) { tv[u] = -INFINITY; ti[u] = 0; }

  auto STAGE = [&](int d, int t) {    // 4 GLDS16 per thread -> 32KB tile
    int sub = t >> 4;
    int k0 = (t & 15) * 64;
    int bn = chunk * SCHUNK + sub * 128;
    #pragma unroll
    for (int s4 = 0; s4 < 4; ++s4) {
      int s = wave * 4 + s4;
      const unsigned short* gp;
      if (s < 16) {
        int r = s * 8 + li8;
        gp = Hn + (size_t)(bm + r) * E_DIM + k0 + gslot * 8;
      } else {
        int r = (s - 16) * 8 + li8;
        gp = MKn + (size_t)(bn + r) * E_DIM + k0 + gslot * 8;
      }
      GLDS16(gp, pool + d * 32768 + s * 1024);
    }
  };

  f32x4 acc[4][2];
  #pragma unroll
  for (int i = 0; i < 4; ++i)
    #pragma unroll
    for (int j = 0; j < 2; ++j)
      acc[i][j] = (f32x4){0.f, 0.f, 0.f, 0.f};

  STAGE(0, 0);
  STAGE(1, 1);

  for (int t = 0; t < NSTEP; ++t) {
    int cur = t & 3;
    if (t + 2 < NSTEP) {
      STAGE((t + 2) & 3, t + 2);
      asm volatile("s_waitcnt vmcnt(8)" ::: "memory");   // tile-t's 4 landed (t+1,t+2 in flight)
    } else if (t + 1 < NSTEP) {
      asm volatile("s_waitcnt vmcnt(4)" ::: "memory");
    } else {
      asm volatile("s_waitcnt vmcnt(0)" ::: "memory");
    }
    __builtin_amdgcn_s_barrier();          // single barrier per step
    __builtin_amdgcn_sched_barrier(0);

    short* Ap = (short*)(pool + cur * 32768);
    short* Bp = (short*)(pool + cur * 32768 + 16384);
    #pragma unroll
    for (int ks = 0; ks < 2; ++ks) {
      short8_t af[4], bf[2];
      int kslot = ks * 4 + (lane >> 4);
      #pragma unroll
      for (int mi = 0; mi < 4; ++mi) {
        int r = wr * 64 + mi * 16 + (lane & 15);
        af[mi] = *(const short8_t*)(Ap + r * 64 + ((kslot ^ (r & 7)) * 8));
      }
      #pragma unroll
      for (int ni = 0; ni < 2; ++ni) {
        int r = wc * 32 + ni * 16 + (lane & 15);
        bf[ni] = *(const short8_t*)(Bp + r * 64 + ((kslot ^ (r & 7)) * 8));
      }
      #pragma unroll
      for (int mi = 0; mi < 4; ++mi)
        #pragma unroll
        for (int ni = 0; ni < 2; ++ni)
          acc[mi][ni] = __builtin_amdgcn_mfma_f32_16x16x32_bf16(af[mi], bf[ni], acc[mi][ni], 0, 0, 0);
    }
    __builtin_amdgcn_sched_barrier(0);

    if ((t & 15) == 15) {
      __builtin_amdgcn_s_barrier();   // all waves done reading buf[cur] before scan overwrites
      short* Sp = (short*)(pool + cur * 32768);
      int bn = chunk * SCHUNK + (t >> 4) * 128;
      #pragma unroll
      for (int mi = 0; mi < 4; ++mi) {
        #pragma unroll
        for (int ni = 0; ni < 2; ++ni) {
          int scol = wc * 32 + ni * 16 + (lane & 15);
          #pragma unroll
          for (int r = 0; r < 4; ++r) {
            int srw = wr * 64 + mi * 16 + (lane >> 4) * 4 + r;
            Sp[srw * 128 + (scol ^ ((srw & 15) << 3))] = (short)f2bf(acc[mi][ni][r]);
          }
          acc[mi][ni] = (f32x4){0.f, 0.f, 0.f, 0.f};
        }
      }
      __syncthreads();
      #pragma unroll
      for (int u4 = 0; u4 < 8; ++u4) {
        int col = sl * 32 + u4 * 4;
        const short* p = Sp + srow * 128 + (col ^ ((srow & 15) << 3));
        short4 v4 = *(const short4*)p;
        short vv[4] = {v4.x, v4.y, v4.z, v4.w};
        #pragma unroll
        for (int j = 0; j < 4; ++j) {
          float v = bf2f((unsigned short)vv[j]);
          if (v > tv[0]) {
            int idx = bn + col + j;
            int p_ = 0;
            #pragma unroll
            for (int q = 1; q < TOPK; ++q)
              if (v > tv[q]) { tv[q-1] = tv[q]; ti[q-1] = ti[q]; p_ = q; }
            tv[p_] = v; ti[p_] = idx;
          }
        }
      }
      __syncthreads();   // scan done before buf[cur] restaged (at step t+2)
    }
  }
  size_t base = (((size_t)(bm + srow)) * NCHUNK + chunk) * CANDS + sl * TOPK;
  #pragma unroll
  for (int u = 0; u < TOPK; ++u) { cand_v[base + u] = tv[u]; cand_i[base + u] = ti[u]; }
}

// ---------------- FUSED merge(512->16) + exact fp32 refine -> top-8 ----------------
__global__ __launch_bounds__(256) void merge_refine_kernel(
    const float* __restrict__ cand_v, const int* __restrict__ cand_i,
    const float* __restrict__ hidden, const float* __restrict__ mkeys,
    const float* __restrict__ rinvH, const float* __restrict__ rinvK,
    float* __restrict__ top_v, int* __restrict__ top_i) {
  int row = blockIdx.x;
  int tid = threadIdx.x;
  int wave = tid >> 6, lane = tid & 63;
  __shared__ float hrow[E_DIM];
  __shared__ int   smid[MIDK];
  __shared__ float rv[MIDK];
  __shared__ int   ri[MIDK];

  // all threads stage hrow
  ((float4*)hrow)[tid] = ((const float4*)(hidden + (size_t)row * E_DIM))[tid];

  // wave 0: merge 512 bf16-order candidates -> top-16 indices into smid
  if (wave == 0) {
    size_t base = (size_t)row * (NCHUNK * CANDS);
    float v[8]; int id[8];
    #pragma unroll
    for (int u = 0; u < 8; ++u) {
      v[u]  = cand_v[base + lane*8 + u];
      id[u] = cand_i[base + lane*8 + u];
    }
    for (int t = 0; t < MIDK; ++t) {
      float bvv = v[0]; int bu = 0;
      #pragma unroll
      for (int u = 1; u < 8; ++u) if (v[u] > bvv) { bvv = v[u]; bu = u; }
      float mv = bvv; int ml = lane;
      #pragma unroll
      for (int off = 32; off; off >>= 1) {
        float ov = __shfl_down(mv, off, 64);
        int   ol = __shfl_down(ml, off, 64);
        if (ov > mv) { mv = ov; ml = ol; }
      }
      ml = __shfl(ml, 0, 64);
      if (lane == ml) {
        smid[t] = id[bu];
        v[bu] = -INFINITY;
      }
    }
  }
  __syncthreads();

  // all 4 waves: exact fp32 dot for 16 candidates
  float rh = rinvH[row];
  for (int c = wave; c < MIDK; c += 4) {
    int idx = smid[c];
    const float* kp = mkeys + (size_t)idx * E_DIM;
    float s = 0.f;
    #pragma unroll
    for (int rr = 0; rr < 4; ++rr) {
      float4 kv = *(const float4*)(kp + rr * 256 + lane * 4);
      float4 hv = *(const float4*)(hrow + rr * 256 + lane * 4);
      s += hv.x*kv.x + hv.y*kv.y + hv.z*kv.z + hv.w*kv.w;
    }
    #pragma unroll
    for (int off = 32; off; off >>= 1) s += __shfl_down(s, off, 64);
    if (lane == 0) { rv[c] = s * rh * rinvK[idx]; ri[c] = idx; }
  }
  __syncthreads();
  if (tid == 0) {
    bool used[MIDK] = {};
    #pragma unroll
    for (int t = 0; t < TOPK; ++t) {
      float best = -INFINITY; int bi = -1; int bidx = 0x7fffffff;
      for (int c = 0; c < MIDK; ++c) {
        if (used[c]) continue;
        if (rv[c] > best || (rv[c] == best && ri[c] < bidx)) {
          best = rv[c]; bi = c; bidx = ri[c];
        }
      }
      used[bi] = true;
      top_v[(size_t)row * TOPK + t] = best;
      top_i[(size_t)row * TOPK + t] = bidx;
    }
  }
}

// ---------------- MFMA flash attention: Q-in-LDS + dbuf K/V + counted vmcnt ----------------
__global__ __launch_bounds__(256) void flash_mfma_kernel(
    const unsigned short* __restrict__ qb, const unsigned short* __restrict__ kb,
    const unsigned short* __restrict__ vT, const float* __restrict__ MV,
    const float* __restrict__ top_v, const int* __restrict__ top_i,
    unsigned short* __restrict__ ctx) {
  __shared__ __align__(16) char pool[65536];   // Qs 16K | buf0 16K | buf1 16K | P 4x4K
  short* Qs = (short*)pool;
  int qt = blockIdx.x;
  int bh = blockIdx.y;
  int b = bh >> 4, h = bh & 15;
  int tid = threadIdx.x;
  int wave = tid >> 6, lane = tid & 63;
  int g = lane >> 4, c = lane & 15;
  int li8 = lane >> 3;
  int gslot = (lane & 7) ^ li8;
  short* Pw = (short*)(pool + 49152 + wave * 4096);
  const float scale = 0.125f;

  auto STAGEKV = [&](int d, int kv0) {
    #pragma unroll
    for (int j = 0; j < 4; ++j) {
      int s = wave * 4 + j;
      const unsigned short* gp;
      if (s < 8) {
        int r = s * 8 + li8;
        gp = kb + ((size_t)(b * SEQ + kv0 + r)) * E_DIM + h * HD + gslot * 8;
      } else {
        int dd = (s - 8) * 8 + li8;
        gp = vT + ((size_t)(bh * HD + dd)) * SEQ + kv0 + gslot * 8;
      }
      GLDS16(gp, pool + 16384 + d * 16384 + s * 1024);
    }
  };

  #pragma unroll
  for (int j = 0; j < 4; ++j) {
    int s = wave * 4 + j;
    int r = s * 8 + li8;
    const unsigned short* gp = qb + ((size_t)(b * SEQ) + qt * 128 + r) * E_DIM + h * HD + gslot * 8;
    GLDS16(gp, pool + s * 1024);
  }
  STAGEKV(0, 0);
  __syncthreads();

  short8_t aQ[2][2];
  #pragma unroll
  for (int mi = 0; mi < 2; ++mi)
    #pragma unroll
    for (int ks = 0; ks < 2; ++ks) {
      int r = wave * 32 + mi * 16 + c;
      int slot = ks * 4 + g;
      aQ[mi][ks] = *(const short8_t*)(Qs + r * 64 + ((slot ^ (r & 7)) * 8));
    }

  f32x4 oa[2][4];
  #pragma unroll
  for (int mi = 0; mi < 2; ++mi)
    #pragma unroll
    for (int nd = 0; nd < 4; ++nd)
      oa[mi][nd] = (f32x4){0.f, 0.f, 0.f, 0.f};
  float m_[2][4], l_[2][4];
  #pragma unroll
  for (int mi = 0; mi < 2; ++mi)
    #pragma unroll
    for (int r = 0; r < 4; ++r) { m_[mi][r] = -INFINITY; l_[mi][r] = 0.f; }

  for (int kt = 0; kt < SEQ / 64; ++kt) {
    int cur = kt & 1;
    if (kt + 1 < SEQ / 64) {
      STAGEKV(1 - cur, (kt + 1) * 64);
      asm volatile("s_waitcnt vmcnt(4)" ::: "memory");
    } else {
      asm volatile("s_waitcnt vmcnt(0)" ::: "memory");
    }
    __builtin_amdgcn_s_barrier();
    __builtin_amdgcn_sched_barrier(0);
    short* Kp = (short*)(pool + 16384 + cur * 16384);
    short* Vp = (short*)(pool + 16384 + cur * 16384 + 8192);

    f32x4 sa[2][4];
    #pragma unroll
    for (int mi = 0; mi < 2; ++mi)
      #pragma unroll
      for (int ni = 0; ni < 4; ++ni)
        sa[mi][ni] = (f32x4){0.f, 0.f, 0.f, 0.f};
    #pragma unroll
    for (int ks = 0; ks < 2; ++ks) {
      short8_t bK[4];
      #pragma unroll
      for (int ni = 0; ni < 4; ++ni) {
        int r = ni * 16 + c;
        bK[ni] = *(const short8_t*)(Kp + r * 64 + (((ks * 4 + g) ^ (r & 7)) * 8));
      }
      #pragma unroll
      for (int mi = 0; mi < 2; ++mi)
        #pragma unroll
        for (int ni = 0; ni < 4; ++ni)
          sa[mi][ni] = __builtin_amdgcn_mfma_f32_16x16x32_bf16(aQ[mi][ks], bK[ni], sa[mi][ni], 0, 0, 0);
    }
    #pragma unroll
    for (int mi = 0; mi < 2; ++mi)
      #pragma unroll
      for (int ni = 0; ni < 4; ++ni)
        #pragma unroll
        for (int r = 0; r < 4; ++r)
          sa[mi][ni][r] *= scale;
    float fsc[2][4];
    #pragma unroll
    for (int mi = 0; mi < 2; ++mi)
      #pragma unroll
      for (int r = 0; r < 4; ++r) {
        float m0 = fmaxf(fmaxf(sa[mi][0][r], sa[mi][1][r]), fmaxf(sa[mi][2][r], sa[mi][3][r]));
        #pragma unroll
        for (int off = 1; off < 16; off <<= 1) m0 = fmaxf(m0, __shfl_xor(m0, off, 64));
        float mn = fmaxf(m_[mi][r], m0);
        fsc[mi][r] = __expf(m_[mi][r] - mn);
        m_[mi][r] = mn;
      }
    #pragma unroll
    for (int mi = 0; mi < 2; ++mi)
      #pragma unroll
      for (int nd = 0; nd < 4; ++nd)
        #pragma unroll
        for (int r = 0; r < 4; ++r)
          oa[mi][nd][r] *= fsc[mi][r];
    #pragma unroll
    for (int mi = 0; mi < 2; ++mi)
      #pragma unroll
      for (int r = 0; r < 4; ++r) {
        float ps = 0.f;
        #pragma unroll
        for (int ni = 0; ni < 4; ++ni) {
          float p = __expf(sa[mi][ni][r] - m_[mi][r]);
          sa[mi][ni][r] = p;
          ps += p;
        }
        #pragma unroll
        for (int off = 1; off < 16; off <<= 1) ps += __shfl_xor(ps, off, 64);
        l_[mi][r] = l_[mi][r] * fsc[mi][r] + ps;
      }
    #pragma unroll
    for (int mi = 0; mi < 2; ++mi)
      #pragma unroll
      for (int ni = 0; ni < 4; ++ni)
        #pragma unroll
        for (int r = 0; r < 4; ++r) {
          int ql = mi * 16 + g * 4 + r;
          int slot = (ni * 2 + (c >> 3)) ^ (ql & 7);
          Pw[ql * 64 + slot * 8 + (c & 7)] = (short)f2bf(sa[mi][ni][r]);
        }
    #pragma unroll
    for (int ks = 0; ks < 2; ++ks) {
      short8_t aP[2], bV[4];
      #pragma unroll
      for (int mi = 0; mi < 2; ++mi) {
        int ql = mi * 16 + c;
        aP[mi] = *(const short8_t*)(Pw + ql * 64 + (((ks * 4 + g) ^ (ql & 7)) * 8));
      }
      #pragma unroll
      for (int nd = 0; nd < 4; ++nd) {
        int dr = nd * 16 + c;
        bV[nd] = *(const short8_t*)(Vp + dr * 64 + (((ks * 4 + g) ^ (dr & 7)) * 8));
      }
      #pragma unroll
      for (int mi = 0; mi < 2; ++mi)
        #pragma unroll
        for (int nd = 0; nd < 4; ++nd)
          oa[mi][nd] = __builtin_amdgcn_mfma_f32_16x16x32_bf16(aP[mi], bV[nd], oa[mi][nd], 0, 0, 0);
    }
    __builtin_amdgcn_sched_barrier(0);
    __builtin_amdgcn_s_barrier();
  }

  #pragma unroll
  for (int mi = 0; mi < 2; ++mi)
    #pragma unroll
    for (int r = 0; r < 4; ++r) {
      size_t row = (size_t)b * SEQ + qt * 128 + wave * 32 + mi * 16 + g * 4 + r;
      const float* tvp = top_v + row * TOPK;
      const int*   tip = top_i + row * TOPK;
      float lg[TOPK];
      float mmax = m_[mi][r];
      #pragma unroll
      for (int j = 0; j < TOPK; ++j) { lg[j] = tvp[j]; mmax = fmaxf(mmax, lg[j]); }
      float f = __expf(m_[mi][r] - mmax);
      float l = l_[mi][r] * f;
      #pragma unroll
      for (int nd = 0; nd < 4; ++nd) oa[mi][nd][r] *= f;
      #pragma unroll
      for (int j = 0; j < TOPK; ++j) {
        float p = __expf(lg[j] - mmax);
        l += p;
        const float* mvp = MV + (size_t)tip[j] * E_DIM + h * HD + c;
        #pragma unroll
        for (int nd = 0; nd < 4; ++nd)
          oa[mi][nd][r] = fmaf(p, mvp[nd * 16], oa[mi][nd][r]);
      }
      float inv = 1.0f / l;
      #pragma unroll
      for (int nd = 0; nd < 4; ++nd)
        ctx[row * E_DIM + h * HD + nd * 16 + c] = f2bf(oa[mi][nd][r] * inv);
    }
}

// ---------------- launcher ----------------
extern "C" void kernel_launch(void* const* d_in, const int* in_sizes, int n_in,
                              void* d_out, int out_size, void* d_ws, size_t ws_size,
                              hipStream_t stream) {
  (void)in_sizes; (void)n_in; (void)out_size; (void)ws_size;
  const float* hidden = (const float*)d_in[0];
  const float* mkeys  = (const float*)d_in[1];
  const float* mvals  = (const float*)d_in[2];
  const float* Wq = (const float*)d_in[3];
  const float* bq = (const float*)d_in[4];
  const float* Wk = (const float*)d_in[5];
  const float* bk = (const float*)d_in[6];
  const float* Wv = (const float*)d_in[7];
  const float* bv = (const float*)d_in[8];
  const float* Wo = (const float*)d_in[9];
  const float* bo = (const float*)d_in[10];

  char* ws = (char*)d_ws;
  float* cand_v = (float*)ws;                                  ws += (size_t)R_TOT * NCHUNK * CANDS * 4;
  int*   cand_i = (int*)ws;                                    ws += (size_t)R_TOT * NCHUNK * CANDS * 4;
  float* top_v  = (float*)ws;                                  ws += (size_t)R_TOT * TOPK * 4;
  int*   top_i  = (int*)ws;                                    ws += (size_t)R_TOT * TOPK * 4;
  float* rinvH  = (float*)ws;                                  ws += (size_t)R_TOT * 4;
  float* rinvK  = (float*)ws;                                  ws += (size_t)M_DIM * 4;
  unsigned short* Hn   = (unsigned short*)ws;                  ws += (size_t)R_TOT * E_DIM * 2;
  unsigned short* MKn  = (unsigned short*)ws;                  ws += (size_t)M_DIM * E_DIM * 2;
  unsigned short* hb   = (unsigned short*)ws;                  ws += (size_t)R_TOT * E_DIM * 2;
  unsigned short* wqb  = (unsigned short*)ws;                  ws += (size_t)E_DIM * E_DIM * 2;
  unsigned short* wkb  = (unsigned short*)ws;                  ws += (size_t)E_DIM * E_DIM * 2;
  unsigned short* wvb  = (unsigned short*)ws;                  ws += (size_t)E_DIM * E_DIM * 2;
  unsigned short* wob  = (unsigned short*)ws;                  ws += (size_t)E_DIM * E_DIM * 2;
  unsigned short* q_b  = (unsigned short*)ws;                  ws += (size_t)R_TOT * E_DIM * 2;
  unsigned short* k_b  = (unsigned short*)ws;                  ws += (size_t)R_TOT * E_DIM * 2;
  unsigned short* v_b  = (unsigned short*)ws;                  ws += (size_t)R_TOT * E_DIM * 2;
  unsigned short* vTb  = (unsigned short*)ws;                  ws += (size_t)R_TOT * E_DIM * 2;
  unsigned short* ctxb = (unsigned short*)ws;                  ws += (size_t)R_TOT * E_DIM * 2;

  norm_all_kernel<<<dim3(R_TOT + M_DIM), 256, 0, stream>>>(
      hidden, mkeys, Hn, MKn, hb, rinvH, rinvK);

  int n4w = E_DIM * E_DIM / 4;
  cast_all_kernel<<<dim3(n4w / 256, 4), 256, 0, stream>>>(
      Wq, Wk, Wv, Wo, wqb, wkb, wvb, wob, n4w);

  mfma_gemm_qkv<<<dim3(R_TOT / 128, 3 * E_DIM / 128), 256, 0, stream>>>(
      hb, wqb, wkb, wvb, bq, bk, bv, q_b, k_b, v_b);

  vtrans_kernel<<<dim3(SEQ / 64, BATCH * H_NUM), 256, 0, stream>>>(v_b, vTb);

  sims_topk_kernel<<<dim3(R_TOT / 128, NCHUNK), 512, 0, stream>>>(Hn, MKn, cand_v, cand_i);
  merge_refine_kernel<<<dim3(R_TOT), 256, 0, stream>>>(
      cand_v, cand_i, hidden, mkeys, rinvH, rinvK, top_v, top_i);

  flash_mfma_kernel<<<dim3(SEQ / 128, BATCH * H_NUM), 256, 0, stream>>>(
      q_b, k_b, vTb, mvals, top_v, top_i, ctxb);

  mfma_gemm_out<<<dim3(R_TOT / 128, E_DIM / 128), 256, 0, stream>>>(ctxb, wob, bo, (float*)d_out);
}

// Round 21
// 536.972 us; speedup vs baseline: 1.1637x; 1.0115x over previous
//
#include <hip/hip_runtime.h>
#include <math.h>

#define R_TOT 4096   // B*S
#define E_DIM 1024
#define M_DIM 16384
#define H_NUM 16
#define HD    64
#define SEQ   2048
#define BATCH 2
#define TOPK  8
#define MIDK  16
#define NCHUNK 16
#define SCHUNK 1024
#define CANDS  32

typedef __attribute__((ext_vector_type(8))) short short8_t;
typedef __attribute__((ext_vector_type(4))) float f32x4;

__device__ inline unsigned short f2bf(float x) {
  unsigned u = __float_as_uint(x);
  u = (u + 0x7fff + ((u >> 16) & 1)) >> 16;
  return (unsigned short)u;
}
__device__ inline float bf2f(unsigned short h) {
  return __uint_as_float(((unsigned)h) << 16);
}

#define GLDS16(gp, lp) __builtin_amdgcn_global_load_lds( \
    (const __attribute__((address_space(1))) void*)(gp), \
    (__attribute__((address_space(3))) void*)(lp), 16, 0, 0)

// ---------------- fused L2-normalize + bf16 cast: hidden AND mkeys in one launch ----------------
__global__ __launch_bounds__(256) void norm_all_kernel(
    const float* __restrict__ hidden, const float* __restrict__ mkeys,
    unsigned short* __restrict__ Hn, unsigned short* __restrict__ MKn,
    unsigned short* __restrict__ hb,
    float* __restrict__ rinvH, float* __restrict__ rinvK) {
  int rb = blockIdx.x;
  int tid = threadIdx.x;
  const float* X;
  unsigned short* Y;
  unsigned short* Yraw;
  float* rout;
  int row;
  if (rb < R_TOT) {
    row = rb; X = hidden + (size_t)row * E_DIM;
    Y = Hn + (size_t)row * E_DIM; Yraw = hb + (size_t)row * E_DIM; rout = rinvH + row;
  } else {
    row = rb - R_TOT; X = mkeys + (size_t)row * E_DIM;
    Y = MKn + (size_t)row * E_DIM; Yraw = nullptr; rout = rinvK + row;
  }
  float4 v = ((const float4*)X)[tid];
  float s = v.x*v.x + v.y*v.y + v.z*v.z + v.w*v.w;
  #pragma unroll
  for (int off = 32; off; off >>= 1) s += __shfl_down(s, off, 64);
  __shared__ float wsum[4];
  if ((tid & 63) == 0) wsum[tid >> 6] = s;
  __syncthreads();
  float tot = wsum[0] + wsum[1] + wsum[2] + wsum[3];
  float rinv = 1.0f / fmaxf(sqrtf(tot), 1e-12f);
  if (tid == 0) *rout = rinv;
  ushort4 o;
  o.x = f2bf(v.x * rinv); o.y = f2bf(v.y * rinv);
  o.z = f2bf(v.z * rinv); o.w = f2bf(v.w * rinv);
  ((ushort4*)Y)[tid] = o;
  if (Yraw) {
    ushort4 o2;
    o2.x = f2bf(v.x); o2.y = f2bf(v.y); o2.z = f2bf(v.z); o2.w = f2bf(v.w);
    ((ushort4*)Yraw)[tid] = o2;
  }
}

// ---------------- fused fp32 -> bf16 cast for all four weight matrices ----------------
__global__ __launch_bounds__(256) void cast_all_kernel(
    const float* __restrict__ W0, const float* __restrict__ W1,
    const float* __restrict__ W2, const float* __restrict__ W3,
    unsigned short* __restrict__ Y0, unsigned short* __restrict__ Y1,
    unsigned short* __restrict__ Y2, unsigned short* __restrict__ Y3, int n4) {
  int sel = blockIdx.y;
  const float* X = (sel == 0) ? W0 : (sel == 1) ? W1 : (sel == 2) ? W2 : W3;
  unsigned short* Y = (sel == 0) ? Y0 : (sel == 1) ? Y1 : (sel == 2) ? Y2 : Y3;
  int i = blockIdx.x * 256 + threadIdx.x;
  if (i < n4) {
    float4 v = ((const float4*)X)[i];
    ushort4 o;
    o.x = f2bf(v.x); o.y = f2bf(v.y); o.z = f2bf(v.z); o.w = f2bf(v.w);
    ((ushort4*)Y)[i] = o;
  }
}

// ---------------- pipelined MFMA 128x128 tile body (dbuf + counted vmcnt, 2 barriers/step) ----------------
// Staging addresses strength-reduced: per-thread base pointer + k0 (waves 0-1: A rows
// wave*64+li8..; waves 2-3: B rows wave*64-128+li8..; 8 segments stride 8*E_DIM).
template<int OUT_BF16>
__device__ __forceinline__ void gemm_tile_body_pipe(
    const unsigned short* __restrict__ Ab, const unsigned short* __restrict__ Bb,
    const float* __restrict__ bias, void* __restrict__ C, int N,
    int bm, int bn, char* pool) {
  int tid = threadIdx.x;
  int wave = tid >> 6, lane = tid & 63;
  int wr = wave >> 1, wc = wave & 1;
  int li8 = lane >> 3;
  int gslot = (lane & 7) ^ li8;

  const unsigned short* gbase;
  if (wave < 2) gbase = Ab + ((size_t)(bm + wave * 64 + li8)) * E_DIM + gslot * 8;
  else          gbase = Bb + ((size_t)(bn + wave * 64 - 128 + li8)) * E_DIM + gslot * 8;
  char* lbase = pool + (wave * 8) * 1024;

  auto STAGE = [&](int d, int k0) {   // 8 GLDS16 per thread -> 32KB tile
    const unsigned short* gp = gbase + k0;
    char* lp = lbase + d * 32768;
    #pragma unroll
    for (int s4 = 0; s4 < 8; ++s4)
      GLDS16(gp + (size_t)s4 * 8 * E_DIM, lp + s4 * 1024);
  };

  f32x4 acc[4][4];
  #pragma unroll
  for (int i = 0; i < 4; ++i)
    #pragma unroll
    for (int j = 0; j < 4; ++j)
      acc[i][j] = (f32x4){0.f, 0.f, 0.f, 0.f};

  STAGE(0, 0);

  for (int t = 0; t < E_DIM / 64; ++t) {
    int cur = t & 1;
    if (t + 1 < E_DIM / 64) {
      STAGE(1 - cur, (t + 1) * 64);
      asm volatile("s_waitcnt vmcnt(8)" ::: "memory");
    } else {
      asm volatile("s_waitcnt vmcnt(0)" ::: "memory");
    }
    __builtin_amdgcn_s_barrier();
    __builtin_amdgcn_sched_barrier(0);
    short* Ap = (short*)(pool + cur * 32768);
    short* Bp = (short*)(pool + cur * 32768 + 16384);
    #pragma unroll
    for (int ks = 0; ks < 2; ++ks) {
      short8_t af[4], bf[4];
      int kslot = ks * 4 + (lane >> 4);
      #pragma unroll
      for (int mi = 0; mi < 4; ++mi) {
        int r = wr * 64 + mi * 16 + (lane & 15);
        af[mi] = *(const short8_t*)(Ap + r * 64 + ((kslot ^ (r & 7)) * 8));
      }
      #pragma unroll
      for (int ni = 0; ni < 4; ++ni) {
        int r = wc * 64 + ni * 16 + (lane & 15);
        bf[ni] = *(const short8_t*)(Bp + r * 64 + ((kslot ^ (r & 7)) * 8));
      }
      #pragma unroll
      for (int mi = 0; mi < 4; ++mi)
        #pragma unroll
        for (int ni = 0; ni < 4; ++ni)
          acc[mi][ni] = __builtin_amdgcn_mfma_f32_16x16x32_bf16(af[mi], bf[ni], acc[mi][ni], 0, 0, 0);
    }
    __builtin_amdgcn_sched_barrier(0);
    __builtin_amdgcn_s_barrier();
  }
  #pragma unroll
  for (int mi = 0; mi < 4; ++mi) {
    #pragma unroll
    for (int ni = 0; ni < 4; ++ni) {
      int col = bn + wc * 64 + ni * 16 + (lane & 15);
      float bv = bias[col];
      #pragma unroll
      for (int r = 0; r < 4; ++r) {
        int row = bm + wr * 64 + mi * 16 + (lane >> 4) * 4 + r;
        float v = acc[mi][ni][r] + bv;
        if (OUT_BF16)
          ((unsigned short*)C)[(size_t)row * N + col] = f2bf(v);
        else
          ((float*)C)[(size_t)row * N + col] = v;
      }
    }
  }
}

// ---------------- output GEMM: C = A * Wo^T + bo (fp32 out) ----------------
__global__ __launch_bounds__(256) void mfma_gemm_out(
    const unsigned short* __restrict__ Ab, const unsigned short* __restrict__ Bb,
    const float* __restrict__ bias, float* __restrict__ C) {
  __shared__ __align__(16) char pool[65536];
  gemm_tile_body_pipe<0>(Ab, Bb, bias, C, E_DIM, blockIdx.x * 128, blockIdx.y * 128, pool);
}

// ---------------- batched QKV GEMM: grid.y covers N=3072 ----------------
__global__ __launch_bounds__(256) void mfma_gemm_qkv(
    const unsigned short* __restrict__ hb,
    const unsigned short* __restrict__ wq, const unsigned short* __restrict__ wk,
    const unsigned short* __restrict__ wv,
    const float* __restrict__ bq, const float* __restrict__ bk, const float* __restrict__ bv,
    unsigned short* __restrict__ q_b, unsigned short* __restrict__ k_b,
    unsigned short* __restrict__ v_b) {
  __shared__ __align__(16) char pool[65536];
  int bn_g = blockIdx.y * 128;
  int sel = bn_g >> 10;
  int bn = bn_g & 1023;
  const unsigned short* Bb = (sel == 0) ? wq : (sel == 1) ? wk : wv;
  const float* bias = (sel == 0) ? bq : (sel == 1) ? bk : bv;
  unsigned short* C = (sel == 0) ? q_b : (sel == 1) ? k_b : v_b;
  gemm_tile_body_pipe<1>(hb, Bb, bias, C, E_DIM, blockIdx.x * 128, bn, pool);
}

// ---------------- V transpose: vb[b][s][h][d] -> vT[b][h][d][s] (bf16) ----------------
__global__ __launch_bounds__(256) void vtrans_kernel(const unsigned short* __restrict__ vb,
                                                     unsigned short* __restrict__ vT) {
  int st = blockIdx.x;
  int bh = blockIdx.y;
  int b = bh >> 4, h = bh & 15;
  __shared__ short T[64][72];
  int tid = threadIdx.x;
  #pragma unroll
  for (int it = 0; it < 2; ++it) {
    int idx = tid + it * 256;
    int r = idx >> 3, sl = idx & 7;
    short8_t v = *(const short8_t*)(vb + ((size_t)(b * SEQ + st * 64 + r)) * E_DIM + h * HD + sl * 8);
    *(short8_t*)&T[r][sl * 8] = v;
  }
  __syncthreads();
  int d = tid >> 2, sp = (tid & 3) * 16;
  short8_t o0, o1;
  #pragma unroll
  for (int u = 0; u < 8; ++u) o0[u] = T[sp + u][d];
  #pragma unroll
  for (int u = 0; u < 8; ++u) o1[u] = T[sp + 8 + u][d];
  size_t base = ((size_t)bh * HD + d) * SEQ + st * 64 + sp;
  *(short8_t*)(vT + base) = o0;
  *(short8_t*)(vT + base + 8) = o1;
}

// ---------------- MFMA bf16 sims GEMM + fused top-8: 8-wave QUAD-buffer, ONE barrier/step ----------------
// Staging addresses strength-reduced: waves 0-3 stage A (rows wave*32+li8..),
// waves 4-7 stage B (rows wave*32-128+li8..); per step delta (t&15)<<6, B adds (t>>4)<<17.
#define NSTEP (SCHUNK / 128 * 16)   // 128 K-steps (8 subtiles x 16)

__global__ __launch_bounds__(512) void sims_topk_kernel(
    const unsigned short* __restrict__ Hn, const unsigned short* __restrict__ MKn,
    float* __restrict__ cand_v, int* __restrict__ cand_i) {
  __shared__ __align__(16) char pool[131072];   // buf0..buf3, 32KB each

  int bm = blockIdx.x * 128;
  int chunk = blockIdx.y;

  int tid = threadIdx.x;
  int wave = tid >> 6, lane = tid & 63;
  int wr = wave >> 2, wc = wave & 3;          // 2x4 wave grid, wave tile 64x32
  int srow = tid >> 2, sl = tid & 3;          // scan: 4 lanes/row, 32 cols each
  int li8 = lane >> 3;
  int gslot = (lane & 7) ^ li8;

  float tv[TOPK]; int ti[TOPK];
  #pragma unroll
  for (int u = 0; u < TOPK; ++u) { tv[u] = -INFINITY; ti[u] = 0; }

  bool isB = (wave >= 4);
  const unsigned short* gbase;
  if (!isB) gbase = Hn + ((size_t)(bm + wave * 32 + li8)) * E_DIM + gslot * 8;
  else      gbase = MKn + ((size_t)(chunk * SCHUNK + wave * 32 - 128 + li8)) * E_DIM + gslot * 8;
  char* lbase = pool + (wave * 4) * 1024;

  auto STAGE = [&](int d, int t) {    // 4 GLDS16 per thread -> 32KB tile
    const unsigned short* gp = gbase + ((t & 15) << 6)
                             + (isB ? ((size_t)(t >> 4) << 17) : (size_t)0);
    char* lp = lbase + d * 32768;
    #pragma unroll
    for (int s4 = 0; s4 < 4; ++s4)
      GLDS16(gp + (size_t)s4 * 8 * E_DIM, lp + s4 * 1024);
  };

  f32x4 acc[4][2];
  #pragma unroll
  for (int i = 0; i < 4; ++i)
    #pragma unroll
    for (int j = 0; j < 2; ++j)
      acc[i][j] = (f32x4){0.f, 0.f, 0.f, 0.f};

  STAGE(0, 0);
  STAGE(1, 1);

  for (int t = 0; t < NSTEP; ++t) {
    int cur = t & 3;
    if (t + 2 < NSTEP) {
      STAGE((t + 2) & 3, t + 2);
      asm volatile("s_waitcnt vmcnt(8)" ::: "memory");   // tile-t's 4 landed (t+1,t+2 in flight)
    } else if (t + 1 < NSTEP) {
      asm volatile("s_waitcnt vmcnt(4)" ::: "memory");
    } else {
      asm volatile("s_waitcnt vmcnt(0)" ::: "memory");
    }
    __builtin_amdgcn_s_barrier();          // single barrier per step
    __builtin_amdgcn_sched_barrier(0);

    short* Ap = (short*)(pool + cur * 32768);
    short* Bp = (short*)(pool + cur * 32768 + 16384);
    #pragma unroll
    for (int ks = 0; ks < 2; ++ks) {
      short8_t af[4], bf[2];
      int kslot = ks * 4 + (lane >> 4);
      #pragma unroll
      for (int mi = 0; mi < 4; ++mi) {
        int r = wr * 64 + mi * 16 + (lane & 15);
        af[mi] = *(const short8_t*)(Ap + r * 64 + ((kslot ^ (r & 7)) * 8));
      }
      #pragma unroll
      for (int ni = 0; ni < 2; ++ni) {
        int r = wc * 32 + ni * 16 + (lane & 15);
        bf[ni] = *(const short8_t*)(Bp + r * 64 + ((kslot ^ (r & 7)) * 8));
      }
      #pragma unroll
      for (int mi = 0; mi < 4; ++mi)
        #pragma unroll
        for (int ni = 0; ni < 2; ++ni)
          acc[mi][ni] = __builtin_amdgcn_mfma_f32_16x16x32_bf16(af[mi], bf[ni], acc[mi][ni], 0, 0, 0);
    }
    __builtin_amdgcn_sched_barrier(0);

    if ((t & 15) == 15) {
      __builtin_amdgcn_s_barrier();   // all waves done reading buf[cur] before scan overwrites
      short* Sp = (short*)(pool + cur * 32768);
      int bn = chunk * SCHUNK + (t >> 4) * 128;
      #pragma unroll
      for (int mi = 0; mi < 4; ++mi) {
        #pragma unroll
        for (int ni = 0; ni < 2; ++ni) {
          int scol = wc * 32 + ni * 16 + (lane & 15);
          #pragma unroll
          for (int r = 0; r < 4; ++r) {
            int srw = wr * 64 + mi * 16 + (lane >> 4) * 4 + r;
            Sp[srw * 128 + (scol ^ ((srw & 15) << 3))] = (short)f2bf(acc[mi][ni][r]);
          }
          acc[mi][ni] = (f32x4){0.f, 0.f, 0.f, 0.f};
        }
      }
      __syncthreads();
      #pragma unroll
      for (int u4 = 0; u4 < 8; ++u4) {
        int col = sl * 32 + u4 * 4;
        const short* p = Sp + srow * 128 + (col ^ ((srow & 15) << 3));
        short4 v4 = *(const short4*)p;
        short vv[4] = {v4.x, v4.y, v4.z, v4.w};
        #pragma unroll
        for (int j = 0; j < 4; ++j) {
          float v = bf2f((unsigned short)vv[j]);
          if (v > tv[0]) {
            int idx = bn + col + j;
            int p_ = 0;
            #pragma unroll
            for (int q = 1; q < TOPK; ++q)
              if (v > tv[q]) { tv[q-1] = tv[q]; ti[q-1] = ti[q]; p_ = q; }
            tv[p_] = v; ti[p_] = idx;
          }
        }
      }
      __syncthreads();   // scan done before buf[cur] restaged (at step t+2)
    }
  }
  size_t base = (((size_t)(bm + srow)) * NCHUNK + chunk) * CANDS + sl * TOPK;
  #pragma unroll
  for (int u = 0; u < TOPK; ++u) { cand_v[base + u] = tv[u]; cand_i[base + u] = ti[u]; }
}

// ---------------- FUSED merge(512->16) + exact fp32 refine -> top-8 ----------------
__global__ __launch_bounds__(256) void merge_refine_kernel(
    const float* __restrict__ cand_v, const int* __restrict__ cand_i,
    const float* __restrict__ hidden, const float* __restrict__ mkeys,
    const float* __restrict__ rinvH, const float* __restrict__ rinvK,
    float* __restrict__ top_v, int* __restrict__ top_i) {
  int row = blockIdx.x;
  int tid = threadIdx.x;
  int wave = tid >> 6, lane = tid & 63;
  __shared__ float hrow[E_DIM];
  __shared__ int   smid[MIDK];
  __shared__ float rv[MIDK];
  __shared__ int   ri[MIDK];

  ((float4*)hrow)[tid] = ((const float4*)(hidden + (size_t)row * E_DIM))[tid];

  if (wave == 0) {
    size_t base = (size_t)row * (NCHUNK * CANDS);
    float v[8]; int id[8];
    #pragma unroll
    for (int u = 0; u < 8; ++u) {
      v[u]  = cand_v[base + lane*8 + u];
      id[u] = cand_i[base + lane*8 + u];
    }
    for (int t = 0; t < MIDK; ++t) {
      float bvv = v[0]; int bu = 0;
      #pragma unroll
      for (int u = 1; u < 8; ++u) if (v[u] > bvv) { bvv = v[u]; bu = u; }
      float mv = bvv; int ml = lane;
      #pragma unroll
      for (int off = 32; off; off >>= 1) {
        float ov = __shfl_down(mv, off, 64);
        int   ol = __shfl_down(ml, off, 64);
        if (ov > mv) { mv = ov; ml = ol; }
      }
      ml = __shfl(ml, 0, 64);
      if (lane == ml) {
        smid[t] = id[bu];
        v[bu] = -INFINITY;
      }
    }
  }
  __syncthreads();

  float rh = rinvH[row];
  for (int c = wave; c < MIDK; c += 4) {
    int idx = smid[c];
    const float* kp = mkeys + (size_t)idx * E_DIM;
    float s = 0.f;
    #pragma unroll
    for (int rr = 0; rr < 4; ++rr) {
      float4 kv = *(const float4*)(kp + rr * 256 + lane * 4);
      float4 hv = *(const float4*)(hrow + rr * 256 + lane * 4);
      s += hv.x*kv.x + hv.y*kv.y + hv.z*kv.z + hv.w*kv.w;
    }
    #pragma unroll
    for (int off = 32; off; off >>= 1) s += __shfl_down(s, off, 64);
    if (lane == 0) { rv[c] = s * rh * rinvK[idx]; ri[c] = idx; }
  }
  __syncthreads();
  if (tid == 0) {
    bool used[MIDK] = {};
    #pragma unroll
    for (int t = 0; t < TOPK; ++t) {
      float best = -INFINITY; int bi = -1; int bidx = 0x7fffffff;
      for (int c = 0; c < MIDK; ++c) {
        if (used[c]) continue;
        if (rv[c] > best || (rv[c] == best && ri[c] < bidx)) {
          best = rv[c]; bi = c; bidx = ri[c];
        }
      }
      used[bi] = true;
      top_v[(size_t)row * TOPK + t] = best;
      top_i[(size_t)row * TOPK + t] = bidx;
    }
  }
}

// ---------------- MFMA flash attention: Q-in-LDS + dbuf K/V + counted vmcnt ----------------
// KV staging strength-reduced: waves 0-1 stage K (base + kv0<<10), waves 2-7 stage V (base + kv0).
__global__ __launch_bounds__(256) void flash_mfma_kernel(
    const unsigned short* __restrict__ qb, const unsigned short* __restrict__ kb,
    const unsigned short* __restrict__ vT, const float* __restrict__ MV,
    const float* __restrict__ top_v, const int* __restrict__ top_i,
    unsigned short* __restrict__ ctx) {
  __shared__ __align__(16) char pool[65536];   // Qs 16K | buf0 16K | buf1 16K | P 4x4K
  short* Qs = (short*)pool;
  int qt = blockIdx.x;
  int bh = blockIdx.y;
  int b = bh >> 4, h = bh & 15;
  int tid = threadIdx.x;
  int wave = tid >> 6, lane = tid & 63;
  int g = lane >> 4, c = lane & 15;
  int li8 = lane >> 3;
  int gslot = (lane & 7) ^ li8;
  short* Pw = (short*)(pool + 49152 + wave * 4096);
  const float scale = 0.125f;

  bool isV = (wave >= 2);
  const unsigned short* gbaseKV;
  size_t segstr;
  if (!isV) {
    gbaseKV = kb + ((size_t)(b * SEQ) + wave * 32 + li8) * E_DIM + h * HD + gslot * 8;
    segstr = (size_t)8 * E_DIM;
  } else {
    gbaseKV = vT + ((size_t)(bh * HD) + wave * 32 - 64 + li8) * SEQ + gslot * 8;
    segstr = (size_t)8 * SEQ;
  }
  char* lbaseKV = pool + 16384 + (wave * 4) * 1024;

  auto STAGEKV = [&](int d, int kv0) {
    const unsigned short* gp = gbaseKV + (isV ? (size_t)kv0 : ((size_t)kv0 << 10));
    char* lp = lbaseKV + d * 16384;
    #pragma unroll
    for (int j = 0; j < 4; ++j)
      GLDS16(gp + j * segstr, lp + j * 1024);
  };

  #pragma unroll
  for (int j = 0; j < 4; ++j) {
    int s = wave * 4 + j;
    int r = s * 8 + li8;
    const unsigned short* gp = qb + ((size_t)(b * SEQ) + qt * 128 + r) * E_DIM + h * HD + gslot * 8;
    GLDS16(gp, pool + s * 1024);
  }
  STAGEKV(0, 0);
  __syncthreads();

  short8_t aQ[2][2];
  #pragma unroll
  for (int mi = 0; mi < 2; ++mi)
    #pragma unroll
    for (int ks = 0; ks < 2; ++ks) {
      int r = wave * 32 + mi * 16 + c;
      int slot = ks * 4 + g;
      aQ[mi][ks] = *(const short8_t*)(Qs + r * 64 + ((slot ^ (r & 7)) * 8));
    }

  f32x4 oa[2][4];
  #pragma unroll
  for (int mi = 0; mi < 2; ++mi)
    #pragma unroll
    for (int nd = 0; nd < 4; ++nd)
      oa[mi][nd] = (f32x4){0.f, 0.f, 0.f, 0.f};
  float m_[2][4], l_[2][4];
  #pragma unroll
  for (int mi = 0; mi < 2; ++mi)
    #pragma unroll
    for (int r = 0; r < 4; ++r) { m_[mi][r] = -INFINITY; l_[mi][r] = 0.f; }

  for (int kt = 0; kt < SEQ / 64; ++kt) {
    int cur = kt & 1;
    if (kt + 1 < SEQ / 64) {
      STAGEKV(1 - cur, (kt + 1) * 64);
      asm volatile("s_waitcnt vmcnt(4)" ::: "memory");
    } else {
      asm volatile("s_waitcnt vmcnt(0)" ::: "memory");
    }
    __builtin_amdgcn_s_barrier();
    __builtin_amdgcn_sched_barrier(0);
    short* Kp = (short*)(pool + 16384 + cur * 16384);
    short* Vp = (short*)(pool + 16384 + cur * 16384 + 8192);

    f32x4 sa[2][4];
    #pragma unroll
    for (int mi = 0; mi < 2; ++mi)
      #pragma unroll
      for (int ni = 0; ni < 4; ++ni)
        sa[mi][ni] = (f32x4){0.f, 0.f, 0.f, 0.f};
    #pragma unroll
    for (int ks = 0; ks < 2; ++ks) {
      short8_t bK[4];
      #pragma unroll
      for (int ni = 0; ni < 4; ++ni) {
        int r = ni * 16 + c;
        bK[ni] = *(const short8_t*)(Kp + r * 64 + (((ks * 4 + g) ^ (r & 7)) * 8));
      }
      #pragma unroll
      for (int mi = 0; mi < 2; ++mi)
        #pragma unroll
        for (int ni = 0; ni < 4; ++ni)
          sa[mi][ni] = __builtin_amdgcn_mfma_f32_16x16x32_bf16(aQ[mi][ks], bK[ni], sa[mi][ni], 0, 0, 0);
    }
    #pragma unroll
    for (int mi = 0; mi < 2; ++mi)
      #pragma unroll
      for (int ni = 0; ni < 4; ++ni)
        #pragma unroll
        for (int r = 0; r < 4; ++r)
          sa[mi][ni][r] *= scale;
    float fsc[2][4];
    #pragma unroll
    for (int mi = 0; mi < 2; ++mi)
      #pragma unroll
      for (int r = 0; r < 4; ++r) {
        float m0 = fmaxf(fmaxf(sa[mi][0][r], sa[mi][1][r]), fmaxf(sa[mi][2][r], sa[mi][3][r]));
        #pragma unroll
        for (int off = 1; off < 16; off <<= 1) m0 = fmaxf(m0, __shfl_xor(m0, off, 64));
        float mn = fmaxf(m_[mi][r], m0);
        fsc[mi][r] = __expf(m_[mi][r] - mn);
        m_[mi][r] = mn;
      }
    #pragma unroll
    for (int mi = 0; mi < 2; ++mi)
      #pragma unroll
      for (int nd = 0; nd < 4; ++nd)
        #pragma unroll
        for (int r = 0; r < 4; ++r)
          oa[mi][nd][r] *= fsc[mi][r];
    #pragma unroll
    for (int mi = 0; mi < 2; ++mi)
      #pragma unroll
      for (int r = 0; r < 4; ++r) {
        float ps = 0.f;
        #pragma unroll
        for (int ni = 0; ni < 4; ++ni) {
          float p = __expf(sa[mi][ni][r] - m_[mi][r]);
          sa[mi][ni][r] = p;
          ps += p;
        }
        #pragma unroll
        for (int off = 1; off < 16; off <<= 1) ps += __shfl_xor(ps, off, 64);
        l_[mi][r] = l_[mi][r] * fsc[mi][r] + ps;
      }
    #pragma unroll
    for (int mi = 0; mi < 2; ++mi)
      #pragma unroll
      for (int ni = 0; ni < 4; ++ni)
        #pragma unroll
        for (int r = 0; r < 4; ++r) {
          int ql = mi * 16 + g * 4 + r;
          int slot = (ni * 2 + (c >> 3)) ^ (ql & 7);
          Pw[ql * 64 + slot * 8 + (c & 7)] = (short)f2bf(sa[mi][ni][r]);
        }
    #pragma unroll
    for (int ks = 0; ks < 2; ++ks) {
      short8_t aP[2], bV[4];
      #pragma unroll
      for (int mi = 0; mi < 2; ++mi) {
        int ql = mi * 16 + c;
        aP[mi] = *(const short8_t*)(Pw + ql * 64 + (((ks * 4 + g) ^ (ql & 7)) * 8));
      }
      #pragma unroll
      for (int nd = 0; nd < 4; ++nd) {
        int dr = nd * 16 + c;
        bV[nd] = *(const short8_t*)(Vp + dr * 64 + (((ks * 4 + g) ^ (dr & 7)) * 8));
      }
      #pragma unroll
      for (int mi = 0; mi < 2; ++mi)
        #pragma unroll
        for (int nd = 0; nd < 4; ++nd)
          oa[mi][nd] = __builtin_amdgcn_mfma_f32_16x16x32_bf16(aP[mi], bV[nd], oa[mi][nd], 0, 0, 0);
    }
    __builtin_amdgcn_sched_barrier(0);
    __builtin_amdgcn_s_barrier();
  }

  #pragma unroll
  for (int mi = 0; mi < 2; ++mi)
    #pragma unroll
    for (int r = 0; r < 4; ++r) {
      size_t row = (size_t)b * SEQ + qt * 128 + wave * 32 + mi * 16 + g * 4 + r;
      const float* tvp = top_v + row * TOPK;
      const int*   tip = top_i + row * TOPK;
      float lg[TOPK];
      float mmax = m_[mi][r];
      #pragma unroll
      for (int j = 0; j < TOPK; ++j) { lg[j] = tvp[j]; mmax = fmaxf(mmax, lg[j]); }
      float f = __expf(m_[mi][r] - mmax);
      float l = l_[mi][r] * f;
      #pragma unroll
      for (int nd = 0; nd < 4; ++nd) oa[mi][nd][r] *= f;
      #pragma unroll
      for (int j = 0; j < TOPK; ++j) {
        float p = __expf(lg[j] - mmax);
        l += p;
        const float* mvp = MV + (size_t)tip[j] * E_DIM + h * HD + c;
        #pragma unroll
        for (int nd = 0; nd < 4; ++nd)
          oa[mi][nd][r] = fmaf(p, mvp[nd * 16], oa[mi][nd][r]);
      }
      float inv = 1.0f / l;
      #pragma unroll
      for (int nd = 0; nd < 4; ++nd)
        ctx[row * E_DIM + h * HD + nd * 16 + c] = f2bf(oa[mi][nd][r] * inv);
    }
}

// ---------------- launcher ----------------
extern "C" void kernel_launch(void* const* d_in, const int* in_sizes, int n_in,
                              void* d_out, int out_size, void* d_ws, size_t ws_size,
                              hipStream_t stream) {
  (void)in_sizes; (void)n_in; (void)out_size; (void)ws_size;
  const float* hidden = (const float*)d_in[0];
  const float* mkeys  = (const float*)d_in[1];
  const float* mvals  = (const float*)d_in[2];
  const float* Wq = (const float*)d_in[3];
  const float* bq = (const float*)d_in[4];
  const float* Wk = (const float*)d_in[5];
  const float* bk = (const float*)d_in[6];
  const float* Wv = (const float*)d_in[7];
  const float* bv = (const float*)d_in[8];
  const float* Wo = (const float*)d_in[9];
  const float* bo = (const float*)d_in[10];

  char* ws = (char*)d_ws;
  float* cand_v = (float*)ws;                                  ws += (size_t)R_TOT * NCHUNK * CANDS * 4;
  int*   cand_i = (int*)ws;                                    ws += (size_t)R_TOT * NCHUNK * CANDS * 4;
  float* top_v  = (float*)ws;                                  ws += (size_t)R_TOT * TOPK * 4;
  int*   top_i  = (int*)ws;                                    ws += (size_t)R_TOT * TOPK * 4;
  float* rinvH  = (float*)ws;                                  ws += (size_t)R_TOT * 4;
  float* rinvK  = (float*)ws;                                  ws += (size_t)M_DIM * 4;
  unsigned short* Hn   = (unsigned short*)ws;                  ws += (size_t)R_TOT * E_DIM * 2;
  unsigned short* MKn  = (unsigned short*)ws;                  ws += (size_t)M_DIM * E_DIM * 2;
  unsigned short* hb   = (unsigned short*)ws;                  ws += (size_t)R_TOT * E_DIM * 2;
  unsigned short* wqb  = (unsigned short*)ws;                  ws += (size_t)E_DIM * E_DIM * 2;
  unsigned short* wkb  = (unsigned short*)ws;                  ws += (size_t)E_DIM * E_DIM * 2;
  unsigned short* wvb  = (unsigned short*)ws;                  ws += (size_t)E_DIM * E_DIM * 2;
  unsigned short* wob  = (unsigned short*)ws;                  ws += (size_t)E_DIM * E_DIM * 2;
  unsigned short* q_b  = (unsigned short*)ws;                  ws += (size_t)R_TOT * E_DIM * 2;
  unsigned short* k_b  = (unsigned short*)ws;                  ws += (size_t)R_TOT * E_DIM * 2;
  unsigned short* v_b  = (unsigned short*)ws;                  ws += (size_t)R_TOT * E_DIM * 2;
  unsigned short* vTb  = (unsigned short*)ws;                  ws += (size_t)R_TOT * E_DIM * 2;
  unsigned short* ctxb = (unsigned short*)ws;                  ws += (size_t)R_TOT * E_DIM * 2;

  norm_all_kernel<<<dim3(R_TOT + M_DIM), 256, 0, stream>>>(
      hidden, mkeys, Hn, MKn, hb, rinvH, rinvK);

  int n4w = E_DIM * E_DIM / 4;
  cast_all_kernel<<<dim3(n4w / 256, 4), 256, 0, stream>>>(
      Wq, Wk, Wv, Wo, wqb, wkb, wvb, wob, n4w);

  mfma_gemm_qkv<<<dim3(R_TOT / 128, 3 * E_DIM / 128), 256, 0, stream>>>(
      hb, wqb, wkb, wvb, bq, bk, bv, q_b, k_b, v_b);

  vtrans_kernel<<<dim3(SEQ / 64, BATCH * H_NUM), 256, 0, stream>>>(v_b, vTb);

  sims_topk_kernel<<<dim3(R_TOT / 128, NCHUNK), 512, 0, stream>>>(Hn, MKn, cand_v, cand_i);
  merge_refine_kernel<<<dim3(R_TOT), 256, 0, stream>>>(
      cand_v, cand_i, hidden, mkeys, rinvH, rinvK, top_v, top_i);

  flash_mfma_kernel<<<dim3(SEQ / 128, BATCH * H_NUM), 256, 0, stream>>>(
      q_b, k_b, vTb, mvals, top_v, top_i, ctxb);

  mfma_gemm_out<<<dim3(R_TOT / 128, E_DIM / 128), 256, 0, stream>>>(ctxb, wob, bo, (float*)d_out);
}